// Round 10
// baseline (491.098 us; speedup 1.0000x reference)
//
#include <hip/hip_runtime.h>
#include <math.h>

#define SB 1024   // seq len
#define DM 1024   // d_model
#define BB 4      // batch
#define NH 16     // heads
#define DH 64     // head dim
#define ML 1024   // MAX_LEN

typedef __attribute__((ext_vector_type(8))) short short8;
typedef __attribute__((ext_vector_type(8))) _Float16 half8;
typedef __attribute__((ext_vector_type(4))) float f32x4;
typedef unsigned short u16;

__device__ __forceinline__ u16 f2bf(float x) {
  unsigned u = __float_as_uint(x);
  u += 0x7fffu + ((u >> 16) & 1u);
  return (u16)(u >> 16);
}
__device__ __forceinline__ float bf2f(u16 h) { return __uint_as_float((unsigned)h << 16); }

// async global->LDS, 16B per lane; lds base must be wave-uniform (HW adds lane*16)
__device__ __forceinline__ void async16(void* lds, const void* g) {
  __builtin_amdgcn_global_load_lds(
      (const __attribute__((address_space(1))) unsigned*)g,
      (__attribute__((address_space(3))) unsigned*)lds, 16, 0, 0);
}

// ---------------- fused: LayerNorm -> split-fp16 frag-chunk planes ----------------
// Block = 16 rows; thread (r16 = t>>4, ks = t&15) owns row rt*16+r16, cols ks*64..+63.
// Row reduction = 4-step shfl over the 16 consecutive lanes sharing r16.
__global__ __launch_bounds__(256) void ln_pack16(const float* __restrict__ x,
    const float* __restrict__ gamma, const float* __restrict__ beta,
    _Float16* __restrict__ dH, _Float16* __restrict__ dL) {
  int rt = blockIdx.x;
  int t = threadIdx.x;
  int r16 = t >> 4, ks = t & 15;
  const float* sp = x + (size_t)(rt * 16 + r16) * 1024 + ks * 64;
  float v[64];
  float s1 = 0.f, s2 = 0.f;
  #pragma unroll
  for (int i = 0; i < 16; ++i) {
    float4 f = *(const float4*)(sp + i * 4);
    v[i*4+0] = f.x; v[i*4+1] = f.y; v[i*4+2] = f.z; v[i*4+3] = f.w;
    s1 += f.x + f.y + f.z + f.w;
    s2 += f.x*f.x + f.y*f.y + f.z*f.z + f.w*f.w;
  }
  #pragma unroll
  for (int off = 1; off < 16; off <<= 1) {
    s1 += __shfl_xor(s1, off, 64);
    s2 += __shfl_xor(s2, off, 64);
  }
  float mu = s1 * (1.0f / 1024.0f);
  float var = s2 * (1.0f / 1024.0f) - mu * mu;
  float rstd = rsqrtf(var + 1e-5f);
  #pragma unroll
  for (int hf = 0; hf < 2; ++hf) {
    int kt = ks * 2 + hf;
    #pragma unroll
    for (int gg = 0; gg < 4; ++gg) {
      const float* gp = gamma + ks * 64 + hf * 32 + gg * 8;
      const float* bp = beta  + ks * 64 + hf * 32 + gg * 8;
      half8 hv, lv;
      #pragma unroll
      for (int j = 0; j < 8; ++j) {
        float xn = (v[hf * 32 + gg * 8 + j] - mu) * rstd * gp[j] + bp[j];
        _Float16 h = (_Float16)xn;
        hv[j] = h;
        lv[j] = (_Float16)(xn - (float)h);
      }
      size_t off = ((size_t)(rt * 32 + kt) * 64 + r16 + gg * 16) * 8;
      *(half8*)(dH + off) = hv;
      *(half8*)(dL + off) = lv;
    }
  }
}

// ---------------- pack fp32 [R][1024] -> split-fp16 frag-chunk planes ----------------
__global__ __launch_bounds__(256) void pack16(const float* __restrict__ src,
    _Float16* __restrict__ dH, _Float16* __restrict__ dL, float scale) {
  int rt = blockIdx.x;
  int t = threadIdx.x;
  int r16 = t >> 4, ks = t & 15;
  const float* sp = src + (size_t)(rt * 16 + r16) * 1024 + ks * 64;
  float v[64];
  #pragma unroll
  for (int i = 0; i < 16; ++i) {
    float4 f = *(const float4*)(sp + i * 4);
    v[i*4+0] = f.x; v[i*4+1] = f.y; v[i*4+2] = f.z; v[i*4+3] = f.w;
  }
  #pragma unroll
  for (int hf = 0; hf < 2; ++hf) {
    int kt = ks * 2 + hf;
    #pragma unroll
    for (int gg = 0; gg < 4; ++gg) {
      half8 hv, lv;
      #pragma unroll
      for (int j = 0; j < 8; ++j) {
        float x = v[hf * 32 + gg * 8 + j] * scale;
        _Float16 h = (_Float16)x;
        hv[j] = h;
        lv[j] = (_Float16)(x - (float)h);
      }
      size_t off = ((size_t)(rt * 32 + kt) * 64 + r16 + gg * 16) * 8;
      *(half8*)(dH + off) = hv;
      *(half8*)(dL + off) = lv;
    }
  }
}

// ---------------- fused: sinusoidal PE -> split-fp16 frag planes ----------------
__global__ __launch_bounds__(256) void pe_pack16(_Float16* __restrict__ dH,
    _Float16* __restrict__ dL) {
  int rt = blockIdx.x;
  int t = threadIdx.x;
  int r16 = t >> 4, ks = t & 15;
  int p = rt * 16 + r16;             // position (row)
  float v[64];
  #pragma unroll
  for (int i = 0; i < 32; ++i) {
    int c0 = ks * 64 + 2 * i;
    float div = expf((float)c0 * (-9.210340371976184f / (float)DM));
    float ang = (float)p * div;
    v[2*i]   = sinf(ang);
    v[2*i+1] = cosf(ang);
  }
  #pragma unroll
  for (int hf = 0; hf < 2; ++hf) {
    int kt = ks * 2 + hf;
    #pragma unroll
    for (int gg = 0; gg < 4; ++gg) {
      half8 hv, lv;
      #pragma unroll
      for (int j = 0; j < 8; ++j) {
        float x = v[hf * 32 + gg * 8 + j];
        _Float16 h = (_Float16)x;
        hv[j] = h;
        lv[j] = (_Float16)(x - (float)h);
      }
      size_t off = ((size_t)(rt * 32 + kt) * 64 + r16 + gg * 16) * 8;
      *(half8*)(dH + off) = hv;
      *(half8*)(dL + off) = lv;
    }
  }
}

// ---------------- split-fp16 MFMA GEMM (band-aware) ----------------
#define GBM 128
#define GBN 256

__global__ __launch_bounds__(256, 2) void gemm16(
    const _Float16* __restrict__ AH, const _Float16* __restrict__ AL,
    const _Float16* __restrict__ BH, const _Float16* __restrict__ BL,
    int nsplit,
    u16* __restrict__ o0H, u16* __restrict__ o0L, float s0,
    u16* __restrict__ o1H, u16* __restrict__ o1L, float s1,
    u16* __restrict__ o2H, u16* __restrict__ o2L, float s2) {
  __shared__ _Float16 L[32 * 512];
  int t = threadIdx.x;
  int wv = t >> 6, lane = t & 63;
  int wm = wv >> 1, wn = wv & 1;
  int r16 = lane & 15, g = lane >> 4;
  int m0 = blockIdx.y * GBM;
  int n0 = blockIdx.x * GBN;
  int mt0 = m0 >> 4, nt0 = n0 >> 4;
  bool split = (n0 < nsplit);        // block-uniform

  f32x4 acc[4][8];
  #pragma unroll
  for (int i = 0; i < 4; ++i)
    #pragma unroll
    for (int j = 0; j < 8; ++j) acc[i][j] = (f32x4){0.f, 0.f, 0.f, 0.f};

  for (int kt = 0; kt < 32; ++kt) {
    __syncthreads();
    #pragma unroll
    for (int rd = 0; rd < 8; ++rd) {
      int ci = rd * 4 + wv;
      bool isAlo = (ci < 16) && (ci & 1);
      if (!split && isAlo) continue;         // wave-uniform skip
      const _Float16* src;
      if (ci < 16) {
        int mt = ci >> 1, pl = ci & 1;
        const _Float16* P = pl ? AL : AH;
        src = P + ((size_t)((mt0 + mt) * 32 + kt) * 64 + lane) * 8;
      } else {
        int nt = ci - 16;
        src = BH + ((size_t)((nt0 + nt) * 32 + kt) * 64 + lane) * 8;
      }
      async16(&L[ci * 512], src);
    }
    half8 blo[8];
    if (split) {
      #pragma unroll
      for (int j = 0; j < 8; ++j) {
        int ntg = nt0 + wn * 8 + j;
        blo[j] = *(const half8*)(BL + ((size_t)(ntg * 32 + kt) * 64 + lane) * 8);
      }
    }
    __syncthreads();

    half8 ah[4], al[4];
    #pragma unroll
    for (int i = 0; i < 4; ++i)
      ah[i] = *(const half8*)&L[(((wm * 4 + i) * 2 + 0) * 512) + lane * 8];
    if (split) {
      #pragma unroll
      for (int i = 0; i < 4; ++i)
        al[i] = *(const half8*)&L[(((wm * 4 + i) * 2 + 1) * 512) + lane * 8];
    }
    #pragma unroll
    for (int j = 0; j < 8; ++j) {
      half8 bh = *(const half8*)&L[((16 + wn * 8 + j) * 512) + lane * 8];
      #pragma unroll
      for (int i = 0; i < 4; ++i) {
        acc[i][j] = __builtin_amdgcn_mfma_f32_16x16x32_f16(ah[i], bh, acc[i][j], 0, 0, 0);
        if (split) {
          acc[i][j] = __builtin_amdgcn_mfma_f32_16x16x32_f16(al[i], bh, acc[i][j], 0, 0, 0);
          acc[i][j] = __builtin_amdgcn_mfma_f32_16x16x32_f16(ah[i], blo[j], acc[i][j], 0, 0, 0);
        }
      }
    }
  }

  #pragma unroll
  for (int i = 0; i < 4; ++i)
    #pragma unroll
    for (int j = 0; j < 8; ++j) {
      int col = n0 + wn * 128 + j * 16 + r16;
      int band = col >> 10, lc = col & 1023;
      float sc = band == 0 ? s0 : band == 1 ? s1 : s2;
      u16* oh = band == 0 ? o0H : band == 1 ? o1H : o2H;
      u16* ol = band == 0 ? o0L : band == 1 ? o1L : o2L;
      #pragma unroll
      for (int reg = 0; reg < 4; ++reg) {
        int row = m0 + wm * 64 + i * 16 + g * 4 + reg;
        float c = acc[i][j][reg] * sc;
        u16 hi = f2bf(c);
        oh[(size_t)row * 1024 + lc] = hi;
        if (ol) ol[(size_t)row * 1024 + lc] = f2bf(c - bf2f(hi));
      }
    }
}

// ---------------- pack V (bf16 [B*S][1024] cols h*64+d) -> frag chunks ----------------
__global__ __launch_bounds__(256) void pack_v(const u16* __restrict__ VHg,
    u16* __restrict__ Vf) {
  int sg = blockIdx.x;
  int h = blockIdx.y, b = blockIdx.z;
  int bh = b * NH + h;
  int t = threadIdx.x;
  int r = t >> 2, q = t & 3;
  int s = sg * 64 + r;
  int kc = s >> 5, g = (s >> 3) & 3, j = s & 7;
  const u16* sp = VHg + (size_t)(b * SB + s) * 1024 + h * 64 + q * 16;
  u16 vv[16];
  *(short8*)&vv[0] = *(const short8*)sp;
  *(short8*)&vv[8] = *(const short8*)(sp + 8);
  u16* dp = Vf + ((size_t)(bh * 32 + kc) * 4 + q) * 512 + g * 128 + j;
  #pragma unroll
  for (int e = 0; e < 16; ++e) dp[e * 8] = vv[e];
}

// ---------------- pack K split-bf16 planes -> MFMA B-frag chunks ----------------
__global__ __launch_bounds__(256) void pack_kf(
    const u16* __restrict__ KH, const u16* __restrict__ KL,
    const u16* __restrict__ pKH, const u16* __restrict__ pKL,
    u16* __restrict__ KtfH, u16* __restrict__ KtfL,
    u16* __restrict__ KpfH, u16* __restrict__ KpfL) {
  int sq = blockIdx.x;
  int h = blockIdx.y, z = blockIdx.z;
  int t = threadIdx.x;
  int u = t >> 6, lane = t & 63;
  #pragma unroll
  for (int it = 0; it < 16; ++it) {
    int uu = it * 4 + u;
    int stl = uu >> 2, c = (uu >> 1) & 1, pl = uu & 1;
    int st = sq * 16 + stl;
    size_t roff = (size_t)(st * 16 + (lane & 15)) * 1024 + h * 64 + c * 32 + (lane >> 4) * 8;
    const u16* src;
    u16* dst;
    if (z < BB) {
      src = (pl ? KL : KH) + (size_t)z * SB * 1024 + roff;
      dst = (pl ? KtfL : KtfH) + ((size_t)((z * NH + h) * 64 + st) * 2 + c) * 512 + lane * 8;
    } else {
      src = (pl ? pKL : pKH) + roff;
      dst = (pl ? KpfL : KpfH) + ((size_t)(h * 64 + st) * 2 + c) * 512 + lane * 8;
    }
    *(short8*)dst = *(const short8*)src;
  }
}

// ---------------- bias table transpose: btT[h][rel] ----------------
__global__ __launch_bounds__(256) void btt_kernel(
    const float* __restrict__ bt, float* __restrict__ btT) {
  int h = blockIdx.x;
  for (int r = threadIdx.x; r < 2 * ML; r += 256)
    btT[(size_t)h * (2 * ML) + r] = bt[(size_t)r * NH + h];
}

// ---------------- MFMA flash attention v8: 2 chains x split-k=2 ----------------
// Round-9 2-chain structure + k-split over blockIdx.y. Grid 1024 -> 4 blocks/CU
// (16 waves/CU, 2x round-9 TLP). (256,4) keeps the 128-VGPR budget the 2-chain
// kernel needs (r7's spill was the 64-reg budget of (256,8); VGPR here is ~120).
// Outputs UNNORMALIZED O (sp0 -> out, sp1 -> O1) + per-row (m,l); combine merges.
__global__ __launch_bounds__(256, 4) void attn_mfma8(
    const u16* __restrict__ KtfH, const u16* __restrict__ KtfL,  // [BH][64][2][512]
    const u16* __restrict__ KpfH, const u16* __restrict__ KpfL,  // [H][64][2][512]
    const u16* __restrict__ QHg, const u16* __restrict__ QLg,    // [B*S][1024] (x IS)
    const u16* __restrict__ pQH, const u16* __restrict__ pQL,    // [S][1024] (x IS)
    const u16* __restrict__ Vf,                                   // [BH][32][4][512]
    const float* __restrict__ btT,
    float* __restrict__ O0, float* __restrict__ O1,
    float2* __restrict__ ml) {                                    // [2][BH][S]
  __shared__ u16 Pb[4][2][16 * 72];
  int bid = blockIdx.x;
  int sp  = blockIdx.y;
  int qt = bid & 7;                  // 8 q-tiles of 128 rows
  int bh = bid >> 3;
  int b = bh >> 4, h = bh & 15;
  int q0 = qt * 128;
  int t = threadIdx.x;
  int wv = t >> 6, lane = t & 63;
  int g = lane >> 4, r16 = lane & 15;

  // ---- Q fragments (A-layout) for both chains
  short8 qhi[2][4], qlo[2][4];
  #pragma unroll
  for (int cc = 0; cc < 2; ++cc) {
    int qrow = q0 + wv * 32 + cc * 16 + r16;
    #pragma unroll
    for (int c = 0; c < 4; ++c) {
      if (c < 2) {
        size_t off = (size_t)(b * SB + qrow) * 1024 + h * DH + c * 32 + g * 8;
        qhi[cc][c] = *(const short8*)(QHg + off);
        qlo[cc][c] = *(const short8*)(QLg + off);
      } else {
        size_t off = (size_t)qrow * 1024 + h * DH + (c - 2) * 32 + g * 8;
        qhi[cc][c] = *(const short8*)(pQH + off);
        qlo[cc][c] = *(const short8*)(pQL + off);
      }
    }
  }

  f32x4 O[2][4];
  #pragma unroll
  for (int cc = 0; cc < 2; ++cc)
    #pragma unroll
    for (int dt = 0; dt < 4; ++dt) O[cc][dt] = (f32x4){0.f, 0.f, 0.f, 0.f};
  float m_run[2][4], l_run[2][4];
  #pragma unroll
  for (int cc = 0; cc < 2; ++cc)
    #pragma unroll
    for (int reg = 0; reg < 4; ++reg) { m_run[cc][reg] = -3e38f; l_run[cc][reg] = 0.f; }

  int qb0 = q0 + wv * 32 + g * 4;    // chain-0 C-layout row base; chain 1: +16
  const u16* ktH = KtfH + (size_t)(bh * 64 + sp * 32) * 1024 + lane * 8;
  const u16* ktL = KtfL + (size_t)(bh * 64 + sp * 32) * 1024 + lane * 8;
  const u16* kpH = KpfH + (size_t)(h * 64 + sp * 32) * 1024 + lane * 8;
  const u16* kpL = KpfL + (size_t)(h * 64 + sp * 32) * 1024 + lane * 8;
  const u16* vp  = Vf + (size_t)(bh * 32 + sp * 16) * 2048 + lane * 8;
  const float* bp0 = btT + (size_t)h * (2 * ML) + ML + sp * 512 + r16 - qb0;
  const float* bp1 = bp0 - 16;

  for (int ktr = 0; ktr < 8; ++ktr) {
    // ---- bias gathers first (independent, prefetchable)
    float bias[2][4][4];
    #pragma unroll
    for (int nt = 0; nt < 4; ++nt)
      #pragma unroll
      for (int reg = 0; reg < 4; ++reg) {
        bias[0][nt][reg] = bp0[nt * 16 - reg];
        bias[1][nt][reg] = bp1[nt * 16 - reg];
      }

    // ---- QK^T: both chains share each K B-frag (3-term split each)
    f32x4 S[2][4];
    #pragma unroll
    for (int nt = 0; nt < 4; ++nt) {
      f32x4 a0 = (f32x4){0.f, 0.f, 0.f, 0.f};
      f32x4 a1 = (f32x4){0.f, 0.f, 0.f, 0.f};
      #pragma unroll
      for (int c = 0; c < 4; ++c) {
        const u16* ph = (c < 2) ? ktH : kpH;
        const u16* pl = (c < 2) ? ktL : kpL;
        int co = (c < 2) ? c : (c - 2);
        short8 bhi = *(const short8*)(ph + nt * 1024 + co * 512);
        short8 blo = *(const short8*)(pl + nt * 1024 + co * 512);
        a0 = __builtin_amdgcn_mfma_f32_16x16x32_bf16(qhi[0][c], bhi, a0, 0, 0, 0);
        a1 = __builtin_amdgcn_mfma_f32_16x16x32_bf16(qhi[1][c], bhi, a1, 0, 0, 0);
        a0 = __builtin_amdgcn_mfma_f32_16x16x32_bf16(qlo[0][c], bhi, a0, 0, 0, 0);
        a1 = __builtin_amdgcn_mfma_f32_16x16x32_bf16(qlo[1][c], bhi, a1, 0, 0, 0);
        a0 = __builtin_amdgcn_mfma_f32_16x16x32_bf16(qhi[0][c], blo, a0, 0, 0, 0);
        a1 = __builtin_amdgcn_mfma_f32_16x16x32_bf16(qhi[1][c], blo, a1, 0, 0, 0);
      }
      S[0][nt] = a0; S[1][nt] = a1;
    }

    // ---- V prefetch: shared by both chains, consumed after softmax
    short8 vfrag[2][4];
    #pragma unroll
    for (int kc = 0; kc < 2; ++kc)
      #pragma unroll
      for (int dt = 0; dt < 4; ++dt)
        vfrag[kc][dt] = *(const short8*)(vp + (kc * 4 + dt) * 512);

    // ---- bias add + online softmax (two chains interleave through the trees)
    #pragma unroll
    for (int cc = 0; cc < 2; ++cc)
      #pragma unroll
      for (int nt = 0; nt < 4; ++nt)
        #pragma unroll
        for (int reg = 0; reg < 4; ++reg)
          S[cc][nt][reg] += bias[cc][nt][reg];

    float tm[2][4], al[2][4];
    #pragma unroll
    for (int cc = 0; cc < 2; ++cc)
      #pragma unroll
      for (int reg = 0; reg < 4; ++reg)
        tm[cc][reg] = fmaxf(fmaxf(S[cc][0][reg], S[cc][1][reg]),
                            fmaxf(S[cc][2][reg], S[cc][3][reg]));
    #pragma unroll
    for (int off = 1; off < 16; off <<= 1)
      #pragma unroll
      for (int cc = 0; cc < 2; ++cc)
        #pragma unroll
        for (int reg = 0; reg < 4; ++reg)
          tm[cc][reg] = fmaxf(tm[cc][reg], __shfl_xor(tm[cc][reg], off, 64));
    #pragma unroll
    for (int cc = 0; cc < 2; ++cc)
      #pragma unroll
      for (int reg = 0; reg < 4; ++reg) {
        float mn = fmaxf(m_run[cc][reg], tm[cc][reg]);
        al[cc][reg] = __expf(m_run[cc][reg] - mn);
        m_run[cc][reg] = mn;
      }
    float ts[2][4] = {{0.f, 0.f, 0.f, 0.f}, {0.f, 0.f, 0.f, 0.f}};
    #pragma unroll
    for (int cc = 0; cc < 2; ++cc)
      #pragma unroll
      for (int nt = 0; nt < 4; ++nt)
        #pragma unroll
        for (int reg = 0; reg < 4; ++reg) {
          float p = __expf(S[cc][nt][reg] - m_run[cc][reg]);
          S[cc][nt][reg] = p;
          ts[cc][reg] += p;
        }
    #pragma unroll
    for (int cc = 0; cc < 2; ++cc)
      #pragma unroll
      for (int reg = 0; reg < 4; ++reg)
        l_run[cc][reg] = l_run[cc][reg] * al[cc][reg] + ts[cc][reg];
    #pragma unroll
    for (int cc = 0; cc < 2; ++cc)
      #pragma unroll
      for (int dt = 0; dt < 4; ++dt)
        #pragma unroll
        for (int reg = 0; reg < 4; ++reg)
          O[cc][dt][reg] *= al[cc][reg];

    // ---- P (C-layout) -> per-wave LDS -> A-layout frags (wave-local ordering)
    #pragma unroll
    for (int cc = 0; cc < 2; ++cc) {
      u16* pb = Pb[wv][cc];
      #pragma unroll
      for (int nt = 0; nt < 4; ++nt)
        #pragma unroll
        for (int reg = 0; reg < 4; ++reg)
          pb[(g * 4 + reg) * 72 + nt * 16 + r16] = f2bf(S[cc][nt][reg]);
    }

    // ---- PV: V frags shared across chains
    #pragma unroll
    for (int kc = 0; kc < 2; ++kc) {
      #pragma unroll
      for (int cc = 0; cc < 2; ++cc) {
        short8 pa = *(const short8*)&Pb[wv][cc][r16 * 72 + kc * 32 + g * 8];
        #pragma unroll
        for (int dt = 0; dt < 4; ++dt)
          O[cc][dt] = __builtin_amdgcn_mfma_f32_16x16x32_bf16(pa, vfrag[kc][dt], O[cc][dt], 0, 0, 0);
      }
    }

    ktH += 4096; ktL += 4096; kpH += 4096; kpL += 4096;
    vp += 4096; bp0 += 64; bp1 += 64;
  }

  // ---- final l reduction across the 16-lane column group
  #pragma unroll
  for (int off = 1; off < 16; off <<= 1)
    #pragma unroll
    for (int cc = 0; cc < 2; ++cc)
      #pragma unroll
      for (int reg = 0; reg < 4; ++reg)
        l_run[cc][reg] += __shfl_xor(l_run[cc][reg], off, 64);

  // ---- write UNNORMALIZED partial O + (m, l)
  float* op = sp ? O1 : O0;
  #pragma unroll
  for (int cc = 0; cc < 2; ++cc)
    #pragma unroll
    for (int dt = 0; dt < 4; ++dt)
      #pragma unroll
      for (int reg = 0; reg < 4; ++reg)
        op[(size_t)(b * SB + qb0 + cc * 16 + reg) * DM + h * DH + dt * 16 + r16] =
            O[cc][dt][reg];
  if (r16 == 0) {
    #pragma unroll
    for (int cc = 0; cc < 2; ++cc)
      #pragma unroll
      for (int reg = 0; reg < 4; ++reg)
        ml[(size_t)(sp * 64 + bh) * SB + qb0 + cc * 16 + reg] =
            make_float2(m_run[cc][reg], l_run[cc][reg]);
  }
}

// ---------------- combine the two k-splits ----------------
__global__ __launch_bounds__(256) void combine_kernel(
    float* __restrict__ out, const float* __restrict__ O1,
    const float2* __restrict__ ml) {
  int row = blockIdx.x;              // b*SB + q
  int b = row >> 10, q = row & 1023;
  int t = threadIdx.x;
  int h = t >> 4;                    // d = t*4 .. t*4+3 -> h = t>>4
  int bh = b * NH + h;
  float2 a0 = ml[(size_t)bh * SB + q];
  float2 a1 = ml[(size_t)(64 + bh) * SB + q];
  float M = fmaxf(a0.x, a1.x);
  float w0 = __expf(a0.x - M), w1 = __expf(a1.x - M);
  float inv = 1.0f / (a0.y * w0 + a1.y * w1);
  float4 c0 = *(const float4*)(out + (size_t)row * DM + t * 4);
  float4 c1 = *(const float4*)(O1 + (size_t)row * DM + t * 4);
  float4 r = {(c0.x * w0 + c1.x * w1) * inv, (c0.y * w0 + c1.y * w1) * inv,
              (c0.z * w0 + c1.z * w1) * inv, (c0.w * w0 + c1.w * w1) * inv};
  *(float4*)(out + (size_t)row * DM + t * 4) = r;
}

extern "C" void kernel_launch(void* const* d_in, const int* in_sizes, int n_in,
                              void* d_out, int out_size, void* d_ws, size_t ws_size,
                              hipStream_t stream) {
  const float* x     = (const float*)d_in[0];
  const float* gamma = (const float*)d_in[1];
  const float* beta  = (const float*)d_in[2];
  const float* w_pos = (const float*)d_in[3];
  const float* w_tok = (const float*)d_in[4];
  const float* bt    = (const float*)d_in[5];
  float* out = (float*)d_out;
  float* ws  = (float*)d_ws;
  const unsigned M1 = 1u << 20;
  const float IS = 11.313708498984761f;  // sqrt(2*dh)

  // Workspace (f32 units, 19M = 76 MB; overlays only on dead regions):
  _Float16* peH   = (_Float16*)(ws + 1 * M1);         // [1,1.5M)  dead after pos gemm
  _Float16* peL   = (_Float16*)(ws + 1 * M1 + M1/2);  // [1.5,2M)
  _Float16* wpH   = (_Float16*)(ws + 2 * M1);         // [2,3M)    dead after pos gemm
  _Float16* wpL   = (_Float16*)(ws + 3 * M1);         // [3,4M)
  u16*      posKH = (u16*)(ws + 4 * M1);              // [4,4.5M)  dead after pack_kf
  u16*      posKL = (u16*)(ws + 4 * M1 + M1/2);       // [4.5,5M)
  u16*      posQH = (u16*)(ws + 5 * M1);              // [5,5.5M)  live -> attn
  u16*      posQL = (u16*)(ws + 5 * M1 + M1/2);       // [5.5,6M)
  _Float16* xnH   = (_Float16*)(ws + 10 * M1);        // [10,12M)  dead after tok gemm
  _Float16* xnL   = (_Float16*)(ws + 12 * M1);        // [12,14M)  dead after tok gemm
  _Float16* wtH   = (_Float16*)(ws + 14 * M1);        // [14,15.5M) dead after tok gemm
  _Float16* wtL   = (_Float16*)(ws + 15 * M1 + M1/2); // [15.5,17M)
  u16*      KH    = (u16*)(ws);                       // [0,2M)    dead after pack_kf
  u16*      KL    = (u16*)(ws + 2 * M1);              // [2,4M)    over wpHL; dead after pack_kf
  u16*      QH    = (u16*)(ws + 6 * M1);              // [6,8M)    live -> attn
  u16*      QL    = (u16*)(ws + 8 * M1);              // [8,10M)
  u16*      VH    = (u16*)(ws + 17 * M1);             // [17,19M)  dead after pack_v
  u16*      Vf    = (u16*)(ws + 10 * M1);             // [10,12M)  over xnH; live -> attn
  float*    btT   = ws + 12 * M1;                     // [12,12.25M) over xnL
  u16*      KpfH  = (u16*)(ws + 12 * M1 + M1/4);      // [12.25,12.75M) 2 MB
  u16*      KpfL  = (u16*)(ws + 12 * M1 + 3*M1/4);    // [12.75,13.25M)
  u16*      KtfH  = (u16*)(ws + 13 * M1 + M1/4);      // [13.25,15.25M) 8 MB
  u16*      KtfL  = (u16*)(ws + 15 * M1 + M1/4);      // [15.25,17.25M)
  float*    O1p   = ws;                               // [0,4M) 16 MB, over KH/KL (dead at attn)
  float2*   mlp   = (float2*)(ws + 4 * M1);           // [4,4.25M) 1 MB, over posK (dead at attn)

  pe_pack16<<<SB / 16, 256, 0, stream>>>(peH, peL);
  pack16<<<(2 * DM) / 16, 256, 0, stream>>>(w_pos, wpH, wpL, 32.0f);
  gemm16<<<dim3((2 * DM) / GBN, SB / GBM), 256, 0, stream>>>(
      peH, peL, wpH, wpL, 2 * DM,
      posKH, posKL, 1.0f / 32.0f,
      posQH, posQL, IS / 32.0f,
      posKH, posKL, 1.0f / 32.0f);
  ln_pack16<<<(BB * SB) / 16, 256, 0, stream>>>(x, gamma, beta, xnH, xnL);
  pack16<<<(3 * DM) / 16, 256, 0, stream>>>(w_tok, wtH, wtL, 32.0f);
  gemm16<<<dim3((3 * DM) / GBN, (BB * SB) / GBM), 256, 0, stream>>>(
      xnH, xnL, wtH, wtL, 2 * DM,          // V band (cols >= 2048): hh-only
      KH, KL, 1.0f / 32.0f,
      QH, QL, IS / 32.0f,
      VH, (u16*)nullptr, 1.0f / 32.0f);
  pack_v<<<dim3(SB / 64, NH, BB), 256, 0, stream>>>(VH, Vf);   // must precede pack_kf (KtfL overlays VH head)
  pack_kf<<<dim3(4, NH, BB + 1), 256, 0, stream>>>(KH, KL, posKH, posKL,
                                                   KtfH, KtfL, KpfH, KpfL);
  btt_kernel<<<NH, 256, 0, stream>>>(bt, btT);
  attn_mfma8<<<dim3(BB * NH * (SB / 128), 2), 256, 0, stream>>>(
      KtfH, KtfL, KpfH, KpfL, QH, QL, posQH, posQL, Vf, btT, out, O1p, mlp);
  combine_kernel<<<BB * SB, 256, 0, stream>>>(out, O1p, mlp);
}

// Round 11
// 320.136 us; speedup vs baseline: 1.5340x; 1.5340x over previous
//
#include <hip/hip_runtime.h>
#include <math.h>

#define SB 1024   // seq len
#define DM 1024   // d_model
#define BB 4      // batch
#define NH 16     // heads
#define DH 64     // head dim
#define ML 1024   // MAX_LEN

typedef __attribute__((ext_vector_type(8))) short short8;
typedef __attribute__((ext_vector_type(8))) _Float16 half8;
typedef __attribute__((ext_vector_type(4))) float f32x4;
typedef unsigned short u16;

__device__ __forceinline__ u16 f2bf(float x) {
  unsigned u = __float_as_uint(x);
  u += 0x7fffu + ((u >> 16) & 1u);
  return (u16)(u >> 16);
}
__device__ __forceinline__ float bf2f(u16 h) { return __uint_as_float((unsigned)h << 16); }

// async global->LDS, 16B per lane; lds base must be wave-uniform (HW adds lane*16)
__device__ __forceinline__ void async16(void* lds, const void* g) {
  __builtin_amdgcn_global_load_lds(
      (const __attribute__((address_space(1))) unsigned*)g,
      (__attribute__((address_space(3))) unsigned*)lds, 16, 0, 0);
}

// ======== S1: fused prep (pe-pack | w_pos-pack | LN-pack | w_tok-pack) ========

__device__ __forceinline__ void pack16_body(int rt, int t, const float* __restrict__ src,
    _Float16* __restrict__ dH, _Float16* __restrict__ dL, float scale) {
  int r16 = t >> 4, ks = t & 15;
  const float* sp = src + (size_t)(rt * 16 + r16) * 1024 + ks * 64;
  float v[64];
  #pragma unroll
  for (int i = 0; i < 16; ++i) {
    float4 f = *(const float4*)(sp + i * 4);
    v[i*4+0] = f.x; v[i*4+1] = f.y; v[i*4+2] = f.z; v[i*4+3] = f.w;
  }
  #pragma unroll
  for (int hf = 0; hf < 2; ++hf) {
    int kt = ks * 2 + hf;
    #pragma unroll
    for (int gg = 0; gg < 4; ++gg) {
      half8 hv, lv;
      #pragma unroll
      for (int j = 0; j < 8; ++j) {
        float x = v[hf * 32 + gg * 8 + j] * scale;
        _Float16 h = (_Float16)x;
        hv[j] = h;
        lv[j] = (_Float16)(x - (float)h);
      }
      size_t off = ((size_t)(rt * 32 + kt) * 64 + r16 + gg * 16) * 8;
      *(half8*)(dH + off) = hv;
      *(half8*)(dL + off) = lv;
    }
  }
}

__device__ __forceinline__ void pe_pack_body(int rt, int t,
    _Float16* __restrict__ dH, _Float16* __restrict__ dL) {
  int r16 = t >> 4, ks = t & 15;
  int p = rt * 16 + r16;
  float v[64];
  #pragma unroll
  for (int i = 0; i < 32; ++i) {
    int c0 = ks * 64 + 2 * i;
    float div = expf((float)c0 * (-9.210340371976184f / (float)DM));
    float ang = (float)p * div;
    v[2*i]   = sinf(ang);
    v[2*i+1] = cosf(ang);
  }
  #pragma unroll
  for (int hf = 0; hf < 2; ++hf) {
    int kt = ks * 2 + hf;
    #pragma unroll
    for (int gg = 0; gg < 4; ++gg) {
      half8 hv, lv;
      #pragma unroll
      for (int j = 0; j < 8; ++j) {
        float x = v[hf * 32 + gg * 8 + j];
        _Float16 h = (_Float16)x;
        hv[j] = h;
        lv[j] = (_Float16)(x - (float)h);
      }
      size_t off = ((size_t)(rt * 32 + kt) * 64 + r16 + gg * 16) * 8;
      *(half8*)(dH + off) = hv;
      *(half8*)(dL + off) = lv;
    }
  }
}

__device__ __forceinline__ void ln_pack_body(int rt, int t, const float* __restrict__ x,
    const float* __restrict__ gamma, const float* __restrict__ beta,
    _Float16* __restrict__ dH, _Float16* __restrict__ dL) {
  int r16 = t >> 4, ks = t & 15;
  const float* sp = x + (size_t)(rt * 16 + r16) * 1024 + ks * 64;
  float v[64];
  float s1 = 0.f, s2 = 0.f;
  #pragma unroll
  for (int i = 0; i < 16; ++i) {
    float4 f = *(const float4*)(sp + i * 4);
    v[i*4+0] = f.x; v[i*4+1] = f.y; v[i*4+2] = f.z; v[i*4+3] = f.w;
    s1 += f.x + f.y + f.z + f.w;
    s2 += f.x*f.x + f.y*f.y + f.z*f.z + f.w*f.w;
  }
  #pragma unroll
  for (int off = 1; off < 16; off <<= 1) {
    s1 += __shfl_xor(s1, off, 64);
    s2 += __shfl_xor(s2, off, 64);
  }
  float mu = s1 * (1.0f / 1024.0f);
  float var = s2 * (1.0f / 1024.0f) - mu * mu;
  float rstd = rsqrtf(var + 1e-5f);
  #pragma unroll
  for (int hf = 0; hf < 2; ++hf) {
    int kt = ks * 2 + hf;
    #pragma unroll
    for (int gg = 0; gg < 4; ++gg) {
      const float* gp = gamma + ks * 64 + hf * 32 + gg * 8;
      const float* bp = beta  + ks * 64 + hf * 32 + gg * 8;
      half8 hv, lv;
      #pragma unroll
      for (int j = 0; j < 8; ++j) {
        float xn = (v[hf * 32 + gg * 8 + j] - mu) * rstd * gp[j] + bp[j];
        _Float16 h = (_Float16)xn;
        hv[j] = h;
        lv[j] = (_Float16)(xn - (float)h);
      }
      size_t off = ((size_t)(rt * 32 + kt) * 64 + r16 + gg * 16) * 8;
      *(half8*)(dH + off) = hv;
      *(half8*)(dL + off) = lv;
    }
  }
}

__global__ __launch_bounds__(256) void prep_all(
    const float* __restrict__ x, const float* __restrict__ gamma,
    const float* __restrict__ beta,
    const float* __restrict__ w_pos, const float* __restrict__ w_tok,
    _Float16* __restrict__ peH, _Float16* __restrict__ peL,
    _Float16* __restrict__ wpH, _Float16* __restrict__ wpL,
    _Float16* __restrict__ xnH, _Float16* __restrict__ xnL,
    _Float16* __restrict__ wtH, _Float16* __restrict__ wtL) {
  int bid = blockIdx.x;
  int t = threadIdx.x;
  if (bid < 64)       pe_pack_body(bid, t, peH, peL);
  else if (bid < 192) pack16_body(bid - 64, t, w_pos, wpH, wpL, 32.0f);
  else if (bid < 448) ln_pack_body(bid - 192, t, x, gamma, beta, xnH, xnL);
  else                pack16_body(bid - 448, t, w_tok, wtH, wtL, 32.0f);
}

// ======== split-fp16 MFMA GEMM, epilogue writes final attn layouts ========
// band (block-uniform, = n0>>10): 0 -> K split-bf16 FRAG planes (fKH/fKL),
//   1 -> Q row-major split-bf16 (qH/qL), 2 -> V frag chunks (vF, hi only).
// Columns >= nsplit: single-pass hh (V band).
#define GBM 128
#define GBN 256

__global__ __launch_bounds__(256, 2) void gemm16f(
    const _Float16* __restrict__ AH, const _Float16* __restrict__ AL,
    const _Float16* __restrict__ BH, const _Float16* __restrict__ BL,
    int nsplit,
    u16* __restrict__ fKH, u16* __restrict__ fKL, float sK,
    u16* __restrict__ qH, u16* __restrict__ qL, float sQ,
    u16* __restrict__ vF, float sV) {
  __shared__ _Float16 L[32 * 512];
  int t = threadIdx.x;
  int wv = t >> 6, lane = t & 63;
  int wm = wv >> 1, wn = wv & 1;
  int r16 = lane & 15, g = lane >> 4;
  int m0 = blockIdx.y * GBM;
  int n0 = blockIdx.x * GBN;
  int mt0 = m0 >> 4, nt0 = n0 >> 4;
  bool split = (n0 < nsplit);        // block-uniform

  f32x4 acc[4][8];
  #pragma unroll
  for (int i = 0; i < 4; ++i)
    #pragma unroll
    for (int j = 0; j < 8; ++j) acc[i][j] = (f32x4){0.f, 0.f, 0.f, 0.f};

  for (int kt = 0; kt < 32; ++kt) {
    __syncthreads();
    #pragma unroll
    for (int rd = 0; rd < 8; ++rd) {
      int ci = rd * 4 + wv;
      bool isAlo = (ci < 16) && (ci & 1);
      if (!split && isAlo) continue;         // wave-uniform skip
      const _Float16* src;
      if (ci < 16) {
        int mt = ci >> 1, pl = ci & 1;
        const _Float16* P = pl ? AL : AH;
        src = P + ((size_t)((mt0 + mt) * 32 + kt) * 64 + lane) * 8;
      } else {
        int nt = ci - 16;
        src = BH + ((size_t)((nt0 + nt) * 32 + kt) * 64 + lane) * 8;
      }
      async16(&L[ci * 512], src);
    }
    half8 blo[8];
    if (split) {
      #pragma unroll
      for (int j = 0; j < 8; ++j) {
        int ntg = nt0 + wn * 8 + j;
        blo[j] = *(const half8*)(BL + ((size_t)(ntg * 32 + kt) * 64 + lane) * 8);
      }
    }
    __syncthreads();

    half8 ah[4], al[4];
    #pragma unroll
    for (int i = 0; i < 4; ++i)
      ah[i] = *(const half8*)&L[(((wm * 4 + i) * 2 + 0) * 512) + lane * 8];
    if (split) {
      #pragma unroll
      for (int i = 0; i < 4; ++i)
        al[i] = *(const half8*)&L[(((wm * 4 + i) * 2 + 1) * 512) + lane * 8];
    }
    #pragma unroll
    for (int j = 0; j < 8; ++j) {
      half8 bh = *(const half8*)&L[((16 + wn * 8 + j) * 512) + lane * 8];
      #pragma unroll
      for (int i = 0; i < 4; ++i) {
        acc[i][j] = __builtin_amdgcn_mfma_f32_16x16x32_f16(ah[i], bh, acc[i][j], 0, 0, 0);
        if (split) {
          acc[i][j] = __builtin_amdgcn_mfma_f32_16x16x32_f16(al[i], bh, acc[i][j], 0, 0, 0);
          acc[i][j] = __builtin_amdgcn_mfma_f32_16x16x32_f16(ah[i], blo[j], acc[i][j], 0, 0, 0);
        }
      }
    }
  }

  int band = n0 >> 10;               // block-uniform (GBN=256 divides 1024)
  if (band == 1) {
    // Q: row-major split-bf16 [row][1024]
    #pragma unroll
    for (int i = 0; i < 4; ++i)
      #pragma unroll
      for (int j = 0; j < 8; ++j) {
        int lc = (n0 & 1023) + wn * 128 + j * 16 + r16;
        #pragma unroll
        for (int reg = 0; reg < 4; ++reg) {
          int row = m0 + wm * 64 + i * 16 + g * 4 + reg;
          float cv = acc[i][j][reg] * sQ;
          u16 hi = f2bf(cv);
          qH[(size_t)row * 1024 + lc] = hi;
          qL[(size_t)row * 1024 + lc] = f2bf(cv - bf2f(hi));
        }
      }
  } else if (band == 0) {
    // K: frag-chunk split-bf16 (layout verified via pack_kf inversion)
    #pragma unroll
    for (int i = 0; i < 4; ++i)
      #pragma unroll
      for (int j = 0; j < 8; ++j) {
        int colg = n0 + wn * 128 + j * 16 + r16;   // < 1024
        int h = colg >> 6, dc = colg & 63;
        #pragma unroll
        for (int reg = 0; reg < 4; ++reg) {
          int row = m0 + wm * 64 + i * 16 + g * 4 + reg;
          int bhK = (row >> 10) * NH + h;          // pos gemm: row<1024 -> bhK=h
          size_t a = ((size_t)((bhK * 64 + ((row & 1023) >> 4)) * 2 + (dc >> 5)) << 9)
                   + ((row & 15) + 16 * ((dc >> 3) & 3)) * 8 + (dc & 7);
          float cv = acc[i][j][reg] * sK;
          u16 hi = f2bf(cv);
          fKH[a] = hi;
          fKL[a] = f2bf(cv - bf2f(hi));
        }
      }
  } else {
    // V: frag chunks, hi only (layout verified via pack_v inversion)
    #pragma unroll
    for (int i = 0; i < 4; ++i)
      #pragma unroll
      for (int j = 0; j < 8; ++j) {
        int colg = (n0 & 1023) + wn * 128 + j * 16 + r16;
        int h = colg >> 6, dc = colg & 63;
        #pragma unroll
        for (int reg = 0; reg < 4; ++reg) {
          int row = m0 + wm * 64 + i * 16 + g * 4 + reg;
          int s = row & 1023;
          size_t a = ((size_t)((((row >> 10) * NH + h) * 32 + (s >> 5)) * 4 + (dc >> 4)) << 9)
                   + ((s >> 3) & 3) * 128 + (s & 7) + (dc & 15) * 8;
          vF[a] = f2bf(acc[i][j][reg] * sV);
        }
      }
  }
}

// ======== MFMA flash attention v9: r9 structure + in-block bias staging ========
// 2 chains x 32 q-rows/wave, barrier-free K-loop, direct global frag loads.
// Bias row for this head gathered from raw bt into LDS once per block.
__global__ __launch_bounds__(256, 2) void attn_mfma9(
    const u16* __restrict__ KtfH, const u16* __restrict__ KtfL,  // [BH][64][2][512]
    const u16* __restrict__ KpfH, const u16* __restrict__ KpfL,  // [H][64][2][512]
    const u16* __restrict__ QHg, const u16* __restrict__ QLg,    // [B*S][1024] (x IS)
    const u16* __restrict__ pQH, const u16* __restrict__ pQL,    // [S][1024] (x IS)
    const u16* __restrict__ Vf,                                   // [BH][32][4][512]
    const float* __restrict__ bt,                                 // [2*ML][NH] raw
    float* __restrict__ out) {
  __shared__ u16 Pb[4][2][16 * 72];
  __shared__ float biasL[2 * ML];
  int bid = blockIdx.x;
  int qt = bid & 7;                  // 8 q-tiles of 128 rows
  int bh = bid >> 3;
  int b = bh >> 4, h = bh & 15;
  int q0 = qt * 128;
  int t = threadIdx.x;
  int wv = t >> 6, lane = t & 63;
  int g = lane >> 4, r16 = lane & 15;

  // ---- stage this head's bias row into LDS (bt is 128KB, L2-hot)
  #pragma unroll
  for (int k = 0; k < 8; ++k)
    biasL[t + k * 256] = bt[(size_t)(t + k * 256) * NH + h];

  // ---- Q fragments (A-layout) for both chains
  short8 qhi[2][4], qlo[2][4];
  #pragma unroll
  for (int cc = 0; cc < 2; ++cc) {
    int qrow = q0 + wv * 32 + cc * 16 + r16;
    #pragma unroll
    for (int c = 0; c < 4; ++c) {
      if (c < 2) {
        size_t off = (size_t)(b * SB + qrow) * 1024 + h * DH + c * 32 + g * 8;
        qhi[cc][c] = *(const short8*)(QHg + off);
        qlo[cc][c] = *(const short8*)(QLg + off);
      } else {
        size_t off = (size_t)qrow * 1024 + h * DH + (c - 2) * 32 + g * 8;
        qhi[cc][c] = *(const short8*)(pQH + off);
        qlo[cc][c] = *(const short8*)(pQL + off);
      }
    }
  }
  __syncthreads();                   // biasL ready

  f32x4 O[2][4];
  #pragma unroll
  for (int cc = 0; cc < 2; ++cc)
    #pragma unroll
    for (int dt = 0; dt < 4; ++dt) O[cc][dt] = (f32x4){0.f, 0.f, 0.f, 0.f};
  float m_run[2][4], l_run[2][4];
  #pragma unroll
  for (int cc = 0; cc < 2; ++cc)
    #pragma unroll
    for (int reg = 0; reg < 4; ++reg) { m_run[cc][reg] = -3e38f; l_run[cc][reg] = 0.f; }

  int qb0 = q0 + wv * 32 + g * 4;    // chain-0 C-layout row base; chain 1: +16
  const u16* ktH = KtfH + (size_t)(bh * 64) * 1024 + lane * 8;
  const u16* ktL = KtfL + (size_t)(bh * 64) * 1024 + lane * 8;
  const u16* kpH = KpfH + (size_t)(h * 64) * 1024 + lane * 8;
  const u16* kpL = KpfL + (size_t)(h * 64) * 1024 + lane * 8;
  const u16* vp  = Vf + (size_t)(bh * 32) * 2048 + lane * 8;
  int bb = ML + r16 - qb0;           // biasL index base, chain 0

  for (int ktr = 0; ktr < 16; ++ktr) {
    // ---- bias from LDS
    float bias[2][4][4];
    #pragma unroll
    for (int nt = 0; nt < 4; ++nt)
      #pragma unroll
      for (int reg = 0; reg < 4; ++reg) {
        bias[0][nt][reg] = biasL[bb + nt * 16 - reg];
        bias[1][nt][reg] = biasL[bb - 16 + nt * 16 - reg];
      }

    // ---- QK^T: both chains share each K B-frag (3-term split each)
    f32x4 S[2][4];
    #pragma unroll
    for (int nt = 0; nt < 4; ++nt) {
      f32x4 a0 = (f32x4){0.f, 0.f, 0.f, 0.f};
      f32x4 a1 = (f32x4){0.f, 0.f, 0.f, 0.f};
      #pragma unroll
      for (int c = 0; c < 4; ++c) {
        const u16* ph = (c < 2) ? ktH : kpH;
        const u16* pl = (c < 2) ? ktL : kpL;
        int co = (c < 2) ? c : (c - 2);
        short8 bhi = *(const short8*)(ph + nt * 1024 + co * 512);
        short8 blo = *(const short8*)(pl + nt * 1024 + co * 512);
        a0 = __builtin_amdgcn_mfma_f32_16x16x32_bf16(qhi[0][c], bhi, a0, 0, 0, 0);
        a1 = __builtin_amdgcn_mfma_f32_16x16x32_bf16(qhi[1][c], bhi, a1, 0, 0, 0);
        a0 = __builtin_amdgcn_mfma_f32_16x16x32_bf16(qlo[0][c], bhi, a0, 0, 0, 0);
        a1 = __builtin_amdgcn_mfma_f32_16x16x32_bf16(qlo[1][c], bhi, a1, 0, 0, 0);
        a0 = __builtin_amdgcn_mfma_f32_16x16x32_bf16(qhi[0][c], blo, a0, 0, 0, 0);
        a1 = __builtin_amdgcn_mfma_f32_16x16x32_bf16(qhi[1][c], blo, a1, 0, 0, 0);
      }
      S[0][nt] = a0; S[1][nt] = a1;
    }

    // ---- V prefetch: shared by both chains, consumed after softmax
    short8 vfrag[2][4];
    #pragma unroll
    for (int kc = 0; kc < 2; ++kc)
      #pragma unroll
      for (int dt = 0; dt < 4; ++dt)
        vfrag[kc][dt] = *(const short8*)(vp + (kc * 4 + dt) * 512);

    // ---- bias add + online softmax (two chains interleave through the trees)
    #pragma unroll
    for (int cc = 0; cc < 2; ++cc)
      #pragma unroll
      for (int nt = 0; nt < 4; ++nt)
        #pragma unroll
        for (int reg = 0; reg < 4; ++reg)
          S[cc][nt][reg] += bias[cc][nt][reg];

    float tm[2][4], al[2][4];
    #pragma unroll
    for (int cc = 0; cc < 2; ++cc)
      #pragma unroll
      for (int reg = 0; reg < 4; ++reg)
        tm[cc][reg] = fmaxf(fmaxf(S[cc][0][reg], S[cc][1][reg]),
                            fmaxf(S[cc][2][reg], S[cc][3][reg]));
    #pragma unroll
    for (int off = 1; off < 16; off <<= 1)
      #pragma unroll
      for (int cc = 0; cc < 2; ++cc)
        #pragma unroll
        for (int reg = 0; reg < 4; ++reg)
          tm[cc][reg] = fmaxf(tm[cc][reg], __shfl_xor(tm[cc][reg], off, 64));
    #pragma unroll
    for (int cc = 0; cc < 2; ++cc)
      #pragma unroll
      for (int reg = 0; reg < 4; ++reg) {
        float mn = fmaxf(m_run[cc][reg], tm[cc][reg]);
        al[cc][reg] = __expf(m_run[cc][reg] - mn);
        m_run[cc][reg] = mn;
      }
    float ts[2][4] = {{0.f, 0.f, 0.f, 0.f}, {0.f, 0.f, 0.f, 0.f}};
    #pragma unroll
    for (int cc = 0; cc < 2; ++cc)
      #pragma unroll
      for (int nt = 0; nt < 4; ++nt)
        #pragma unroll
        for (int reg = 0; reg < 4; ++reg) {
          float p = __expf(S[cc][nt][reg] - m_run[cc][reg]);
          S[cc][nt][reg] = p;
          ts[cc][reg] += p;
        }
    #pragma unroll
    for (int cc = 0; cc < 2; ++cc)
      #pragma unroll
      for (int reg = 0; reg < 4; ++reg)
        l_run[cc][reg] = l_run[cc][reg] * al[cc][reg] + ts[cc][reg];
    #pragma unroll
    for (int cc = 0; cc < 2; ++cc)
      #pragma unroll
      for (int dt = 0; dt < 4; ++dt)
        #pragma unroll
        for (int reg = 0; reg < 4; ++reg)
          O[cc][dt][reg] *= al[cc][reg];

    // ---- P (C-layout) -> per-wave LDS -> A-layout frags (wave-local ordering)
    #pragma unroll
    for (int cc = 0; cc < 2; ++cc) {
      u16* pb = Pb[wv][cc];
      #pragma unroll
      for (int nt = 0; nt < 4; ++nt)
        #pragma unroll
        for (int reg = 0; reg < 4; ++reg)
          pb[(g * 4 + reg) * 72 + nt * 16 + r16] = f2bf(S[cc][nt][reg]);
    }

    // ---- PV: V frags shared across chains
    #pragma unroll
    for (int kc = 0; kc < 2; ++kc) {
      #pragma unroll
      for (int cc = 0; cc < 2; ++cc) {
        short8 pa = *(const short8*)&Pb[wv][cc][r16 * 72 + kc * 32 + g * 8];
        #pragma unroll
        for (int dt = 0; dt < 4; ++dt)
          O[cc][dt] = __builtin_amdgcn_mfma_f32_16x16x32_bf16(pa, vfrag[kc][dt], O[cc][dt], 0, 0, 0);
      }
    }

    ktH += 4096; ktL += 4096; kpH += 4096; kpL += 4096;
    vp += 4096; bb += 64;
  }

  // ---- final l reduction across the 16-lane column group, then normalize
  #pragma unroll
  for (int off = 1; off < 16; off <<= 1)
    #pragma unroll
    for (int cc = 0; cc < 2; ++cc)
      #pragma unroll
      for (int reg = 0; reg < 4; ++reg)
        l_run[cc][reg] += __shfl_xor(l_run[cc][reg], off, 64);
  #pragma unroll
  for (int cc = 0; cc < 2; ++cc)
    #pragma unroll
    for (int reg = 0; reg < 4; ++reg) l_run[cc][reg] = 1.0f / l_run[cc][reg];
  #pragma unroll
  for (int cc = 0; cc < 2; ++cc)
    #pragma unroll
    for (int dt = 0; dt < 4; ++dt)
      #pragma unroll
      for (int reg = 0; reg < 4; ++reg)
        out[(size_t)(b * SB + qb0 + cc * 16 + reg) * DM + h * DH + dt * 16 + r16] =
            O[cc][dt][reg] * l_run[cc][reg];
}

extern "C" void kernel_launch(void* const* d_in, const int* in_sizes, int n_in,
                              void* d_out, int out_size, void* d_ws, size_t ws_size,
                              hipStream_t stream) {
  const float* x     = (const float*)d_in[0];
  const float* gamma = (const float*)d_in[1];
  const float* beta  = (const float*)d_in[2];
  const float* w_pos = (const float*)d_in[3];
  const float* w_tok = (const float*)d_in[4];
  const float* bt    = (const float*)d_in[5];
  float* out = (float*)d_out;
  float* ws  = (float*)d_ws;
  const unsigned M1 = 1u << 20;
  const float IS = 11.313708498984761f;  // sqrt(2*dh)

  // Workspace (f32 units, 19M = 76 MB). Lifetime check:
  //   S2 (pos gemm) reads pe[1,2)+wp[2,4), writes Kpf[4,5)+posQ[5,6).
  //   S3 (tok gemm) reads xn[10,14)+wt[14,17), writes Vf[0,2), KtfL[2,4),
  //      Q[6,10), KtfH[17,19)  (over pe/wp, dead after S2).
  //   S4 (attn) reads Kpf, posQ, Q, Vf, Ktf, bt.
  _Float16* peH   = (_Float16*)(ws + 1 * M1);         // [1,1.5M)
  _Float16* peL   = (_Float16*)(ws + 1 * M1 + M1/2);  // [1.5,2M)
  _Float16* wpH   = (_Float16*)(ws + 2 * M1);         // [2,3M)
  _Float16* wpL   = (_Float16*)(ws + 3 * M1);         // [3,4M)
  u16*      KpfH  = (u16*)(ws + 4 * M1);              // [4,4.5M)
  u16*      KpfL  = (u16*)(ws + 4 * M1 + M1/2);       // [4.5,5M)
  u16*      posQH = (u16*)(ws + 5 * M1);              // [5,5.5M)
  u16*      posQL = (u16*)(ws + 5 * M1 + M1/2);       // [5.5,6M)
  u16*      QH    = (u16*)(ws + 6 * M1);              // [6,8M)
  u16*      QL    = (u16*)(ws + 8 * M1);              // [8,10M)
  _Float16* xnH   = (_Float16*)(ws + 10 * M1);        // [10,12M)
  _Float16* xnL   = (_Float16*)(ws + 12 * M1);        // [12,14M)
  _Float16* wtH   = (_Float16*)(ws + 14 * M1);        // [14,15.5M)
  _Float16* wtL   = (_Float16*)(ws + 15 * M1 + M1/2); // [15.5,17M)
  u16*      Vf    = (u16*)(ws);                       // [0,2M)   over pe (dead)
  u16*      KtfL  = (u16*)(ws + 2 * M1);              // [2,4M)   over wp (dead)
  u16*      KtfH  = (u16*)(ws + 17 * M1);             // [17,19M)

  // S1: all packs fused (64 pe | 128 w_pos | 256 LN | 192 w_tok)
  prep_all<<<640, 256, 0, stream>>>(x, gamma, beta, w_pos, w_tok,
                                    peH, peL, wpH, wpL, xnH, xnL, wtH, wtL);
  // S2: pos = pe @ w_pos^T -> bands {K -> Kpf frag (1/32), Q -> posQ row-major (IS/32)}
  gemm16f<<<dim3((2 * DM) / GBN, SB / GBM), 256, 0, stream>>>(
      peH, peL, wpH, wpL, 2 * DM,
      KpfH, KpfL, 1.0f / 32.0f,
      posQH, posQL, IS / 32.0f,
      (u16*)nullptr, 0.f);
  // S3: tok = xn @ w_tok^T -> bands {K -> Ktf frag (1/32), Q row-major (IS/32),
  //     V -> Vf frag hi-only (1/32, hh-only pass via nsplit)}
  gemm16f<<<dim3((3 * DM) / GBN, (BB * SB) / GBM), 256, 0, stream>>>(
      xnH, xnL, wtH, wtL, 2 * DM,
      KtfH, KtfL, 1.0f / 32.0f,
      QH, QL, IS / 32.0f,
      Vf, 1.0f / 32.0f);
  // S4: attention
  attn_mfma9<<<BB * NH * (SB / 128), 256, 0, stream>>>(
      KtfH, KtfL, KpfH, KpfL, QH, QL, posQH, posQL, Vf, bt, out);
}

// Round 12
// 314.423 us; speedup vs baseline: 1.5619x; 1.0182x over previous
//
#include <hip/hip_runtime.h>
#include <math.h>

#define SB 1024   // seq len
#define DM 1024   // d_model
#define BB 4      // batch
#define NH 16     // heads
#define DH 64     // head dim
#define ML 1024   // MAX_LEN

typedef __attribute__((ext_vector_type(8))) short short8;
typedef __attribute__((ext_vector_type(8))) _Float16 half8;
typedef __attribute__((ext_vector_type(4))) float f32x4;
typedef unsigned short u16;

__device__ __forceinline__ u16 f2bf(float x) {
  unsigned u = __float_as_uint(x);
  u += 0x7fffu + ((u >> 16) & 1u);
  return (u16)(u >> 16);
}
__device__ __forceinline__ float bf2f(u16 h) { return __uint_as_float((unsigned)h << 16); }

// async global->LDS, 16B per lane; lds base must be wave-uniform (HW adds lane*16)
__device__ __forceinline__ void async16(void* lds, const void* g) {
  __builtin_amdgcn_global_load_lds(
      (const __attribute__((address_space(1))) unsigned*)g,
      (__attribute__((address_space(3))) unsigned*)lds, 16, 0, 0);
}

// ======== S1: fused prep (pe-pack | LN-pack) — weights no longer packed ========

__device__ __forceinline__ void pe_pack_body(int rt, int t,
    _Float16* __restrict__ dH, _Float16* __restrict__ dL) {
  int r16 = t >> 4, ks = t & 15;
  int p = rt * 16 + r16;
  float v[64];
  #pragma unroll
  for (int i = 0; i < 32; ++i) {
    int c0 = ks * 64 + 2 * i;
    float div = expf((float)c0 * (-9.210340371976184f / (float)DM));
    float ang = (float)p * div;
    v[2*i]   = sinf(ang);
    v[2*i+1] = cosf(ang);
  }
  #pragma unroll
  for (int hf = 0; hf < 2; ++hf) {
    int kt = ks * 2 + hf;
    #pragma unroll
    for (int gg = 0; gg < 4; ++gg) {
      half8 hv, lv;
      #pragma unroll
      for (int j = 0; j < 8; ++j) {
        float x = v[hf * 32 + gg * 8 + j];
        _Float16 h = (_Float16)x;
        hv[j] = h;
        lv[j] = (_Float16)(x - (float)h);
      }
      size_t off = ((size_t)(rt * 32 + kt) * 64 + r16 + gg * 16) * 8;
      *(half8*)(dH + off) = hv;
      *(half8*)(dL + off) = lv;
    }
  }
}

__device__ __forceinline__ void ln_pack_body(int rt, int t, const float* __restrict__ x,
    const float* __restrict__ gamma, const float* __restrict__ beta,
    _Float16* __restrict__ dH, _Float16* __restrict__ dL) {
  int r16 = t >> 4, ks = t & 15;
  const float* sp = x + (size_t)(rt * 16 + r16) * 1024 + ks * 64;
  float v[64];
  float s1 = 0.f, s2 = 0.f;
  #pragma unroll
  for (int i = 0; i < 16; ++i) {
    float4 f = *(const float4*)(sp + i * 4);
    v[i*4+0] = f.x; v[i*4+1] = f.y; v[i*4+2] = f.z; v[i*4+3] = f.w;
    s1 += f.x + f.y + f.z + f.w;
    s2 += f.x*f.x + f.y*f.y + f.z*f.z + f.w*f.w;
  }
  #pragma unroll
  for (int off = 1; off < 16; off <<= 1) {
    s1 += __shfl_xor(s1, off, 64);
    s2 += __shfl_xor(s2, off, 64);
  }
  float mu = s1 * (1.0f / 1024.0f);
  float var = s2 * (1.0f / 1024.0f) - mu * mu;
  float rstd = rsqrtf(var + 1e-5f);
  #pragma unroll
  for (int hf = 0; hf < 2; ++hf) {
    int kt = ks * 2 + hf;
    #pragma unroll
    for (int gg = 0; gg < 4; ++gg) {
      const float* gp = gamma + ks * 64 + hf * 32 + gg * 8;
      const float* bp = beta  + ks * 64 + hf * 32 + gg * 8;
      half8 hv, lv;
      #pragma unroll
      for (int j = 0; j < 8; ++j) {
        float xn = (v[hf * 32 + gg * 8 + j] - mu) * rstd * gp[j] + bp[j];
        _Float16 h = (_Float16)xn;
        hv[j] = h;
        lv[j] = (_Float16)(xn - (float)h);
      }
      size_t off = ((size_t)(rt * 32 + kt) * 64 + r16 + gg * 16) * 8;
      *(half8*)(dH + off) = hv;
      *(half8*)(dL + off) = lv;
    }
  }
}

__global__ __launch_bounds__(256) void prep_all(
    const float* __restrict__ x, const float* __restrict__ gamma,
    const float* __restrict__ beta,
    _Float16* __restrict__ peH, _Float16* __restrict__ peL,
    _Float16* __restrict__ xnH, _Float16* __restrict__ xnL) {
  int bid = blockIdx.x;
  int t = threadIdx.x;
  if (bid < 64) pe_pack_body(bid, t, peH, peL);
  else          ln_pack_body(bid - 64, t, x, gamma, beta, xnH, xnL);
}

// ======== S2: MERGED split-fp16 MFMA GEMM (tok blocks 0..383, pos 384..447) ========
// A from split-fp16 planes (async16); B staged from ORIGINAL fp32 weights:
// load -> x32 -> split hi/lo in-register -> ds_write (mathematically identical
// to the old prep-side split). Epilogue writes final attn layouts (verified r11):
//   band0 -> K frag planes, band1 -> Q row-major split-bf16, band2 -> V frag (hi).
#define GBM 128
#define GBN 256

__global__ __launch_bounds__(256, 2) void gemm16m(
    const _Float16* __restrict__ AtH, const _Float16* __restrict__ AtL,  // xn planes
    const _Float16* __restrict__ ApH, const _Float16* __restrict__ ApL,  // pe planes
    const float* __restrict__ Wt, const float* __restrict__ Wp,          // fp32 weights
    u16* __restrict__ KtfH, u16* __restrict__ KtfL,
    u16* __restrict__ KpfH, u16* __restrict__ KpfL,
    u16* __restrict__ QH, u16* __restrict__ QL,
    u16* __restrict__ pQH, u16* __restrict__ pQL,
    u16* __restrict__ vF, float sK, float sQ, float sV) {
  __shared__ _Float16 L[48 * 512];   // A:0..15, Bhi:16..31, Blo:32..47 (48 KB)
  int t = threadIdx.x;
  int wv = t >> 6, lane = t & 63;
  int wm = wv >> 1, wn = wv & 1;
  int r16 = lane & 15, g = lane >> 4;

  int bid = blockIdx.x;
  bool isPos = (bid >= 384);
  int idx = isPos ? bid - 384 : bid;
  int n0, m0;
  const _Float16 *AH, *AL;
  const float* W;
  if (isPos) { n0 = (idx & 7) * 256;  m0 = (idx >> 3) * 128; AH = ApH; AL = ApL; W = Wp; }
  else       { n0 = (idx % 12) * 256; m0 = (idx / 12) * 128; AH = AtH; AL = AtL; W = Wt; }
  int mt0 = m0 >> 4, nt0 = n0 >> 4;
  bool split = isPos || (n0 < 2048);   // V band (tok, n0>=2048): hh-only

  f32x4 acc[4][8];
  #pragma unroll
  for (int i = 0; i < 4; ++i)
    #pragma unroll
    for (int j = 0; j < 8; ++j) acc[i][j] = (f32x4){0.f, 0.f, 0.f, 0.f};

  for (int kt = 0; kt < 32; ++kt) {
    __syncthreads();
    // ---- A: 16 chunks (8 mt x 2 planes) via async16; skip lo if !split
    #pragma unroll
    for (int rd = 0; rd < 4; ++rd) {
      int ci = rd * 4 + wv;
      int mt = ci >> 1, pl = ci & 1;
      if (!split && pl) continue;        // wave-uniform
      const _Float16* src = (pl ? AL : AH)
          + ((size_t)((mt0 + mt) * 32 + kt) * 64 + lane) * 8;
      async16(&L[ci * 512], src);
    }
    // ---- B: 16 tiles; each wave stages 4 (fp32 load -> x32 -> split -> LDS)
    #pragma unroll
    for (int tt = 0; tt < 4; ++tt) {
      int nt = wv * 4 + tt;
      const float* wsrc = W + (size_t)((nt0 + nt) * 16 + r16) * 1024 + kt * 32 + g * 8;
      float4 w0 = *(const float4*)wsrc;
      float4 w1 = *(const float4*)(wsrc + 4);
      float wvv[8] = {w0.x, w0.y, w0.z, w0.w, w1.x, w1.y, w1.z, w1.w};
      half8 hv, lv;
      #pragma unroll
      for (int j = 0; j < 8; ++j) {
        float xx = wvv[j] * 32.0f;
        _Float16 h = (_Float16)xx;
        hv[j] = h;
        lv[j] = (_Float16)(xx - (float)h);
      }
      *(half8*)&L[(16 + nt) * 512 + lane * 8] = hv;
      if (split) *(half8*)&L[(32 + nt) * 512 + lane * 8] = lv;
    }
    __syncthreads();

    half8 ah[4], al[4];
    #pragma unroll
    for (int i = 0; i < 4; ++i)
      ah[i] = *(const half8*)&L[(((wm * 4 + i) * 2 + 0) * 512) + lane * 8];
    if (split) {
      #pragma unroll
      for (int i = 0; i < 4; ++i)
        al[i] = *(const half8*)&L[(((wm * 4 + i) * 2 + 1) * 512) + lane * 8];
    }
    #pragma unroll
    for (int j = 0; j < 8; ++j) {
      half8 bh = *(const half8*)&L[((16 + wn * 8 + j) * 512) + lane * 8];
      #pragma unroll
      for (int i = 0; i < 4; ++i) {
        acc[i][j] = __builtin_amdgcn_mfma_f32_16x16x32_f16(ah[i], bh, acc[i][j], 0, 0, 0);
        if (split) {
          half8 bl = *(const half8*)&L[((32 + wn * 8 + j) * 512) + lane * 8];
          acc[i][j] = __builtin_amdgcn_mfma_f32_16x16x32_f16(al[i], bh, acc[i][j], 0, 0, 0);
          acc[i][j] = __builtin_amdgcn_mfma_f32_16x16x32_f16(ah[i], bl, acc[i][j], 0, 0, 0);
        }
      }
    }
  }

  int band = n0 >> 10;                 // block-uniform
  u16* fKH = isPos ? KpfH : KtfH;
  u16* fKL = isPos ? KpfL : KtfL;
  u16* qHo = isPos ? pQH  : QH;
  u16* qLo = isPos ? pQL  : QL;
  if (band == 1) {
    // Q: row-major split-bf16 [row][1024]
    #pragma unroll
    for (int i = 0; i < 4; ++i)
      #pragma unroll
      for (int j = 0; j < 8; ++j) {
        int lc = (n0 & 1023) + wn * 128 + j * 16 + r16;
        #pragma unroll
        for (int reg = 0; reg < 4; ++reg) {
          int row = m0 + wm * 64 + i * 16 + g * 4 + reg;
          float cv = acc[i][j][reg] * sQ;
          u16 hi = f2bf(cv);
          qHo[(size_t)row * 1024 + lc] = hi;
          qLo[(size_t)row * 1024 + lc] = f2bf(cv - bf2f(hi));
        }
      }
  } else if (band == 0) {
    // K: frag-chunk split-bf16 (layout verified r11)
    #pragma unroll
    for (int i = 0; i < 4; ++i)
      #pragma unroll
      for (int j = 0; j < 8; ++j) {
        int colg = n0 + wn * 128 + j * 16 + r16;   // < 1024
        int h = colg >> 6, dc = colg & 63;
        #pragma unroll
        for (int reg = 0; reg < 4; ++reg) {
          int row = m0 + wm * 64 + i * 16 + g * 4 + reg;
          int bhK = (row >> 10) * NH + h;          // pos: row<1024 -> bhK=h
          size_t a = ((size_t)((bhK * 64 + ((row & 1023) >> 4)) * 2 + (dc >> 5)) << 9)
                   + ((row & 15) + 16 * ((dc >> 3) & 3)) * 8 + (dc & 7);
          float cv = acc[i][j][reg] * sK;
          u16 hi = f2bf(cv);
          fKH[a] = hi;
          fKL[a] = f2bf(cv - bf2f(hi));
        }
      }
  } else {
    // V: frag chunks, hi only (layout verified r11)
    #pragma unroll
    for (int i = 0; i < 4; ++i)
      #pragma unroll
      for (int j = 0; j < 8; ++j) {
        int colg = (n0 & 1023) + wn * 128 + j * 16 + r16;
        int h = colg >> 6, dc = colg & 63;
        #pragma unroll
        for (int reg = 0; reg < 4; ++reg) {
          int row = m0 + wm * 64 + i * 16 + g * 4 + reg;
          int s = row & 1023;
          size_t a = ((size_t)((((row >> 10) * NH + h) * 32 + (s >> 5)) * 4 + (dc >> 4)) << 9)
                   + ((s >> 3) & 3) * 128 + (s & 7) + (dc & 15) * 8;
          vF[a] = f2bf(acc[i][j][reg] * sV);
        }
      }
  }
}

// ======== S3: MFMA flash attention (r11 verbatim — verified) ========
__global__ __launch_bounds__(256, 2) void attn_mfma9(
    const u16* __restrict__ KtfH, const u16* __restrict__ KtfL,  // [BH][64][2][512]
    const u16* __restrict__ KpfH, const u16* __restrict__ KpfL,  // [H][64][2][512]
    const u16* __restrict__ QHg, const u16* __restrict__ QLg,    // [B*S][1024] (x IS)
    const u16* __restrict__ pQH, const u16* __restrict__ pQL,    // [S][1024] (x IS)
    const u16* __restrict__ Vf,                                   // [BH][32][4][512]
    const float* __restrict__ bt,                                 // [2*ML][NH] raw
    float* __restrict__ out) {
  __shared__ u16 Pb[4][2][16 * 72];
  __shared__ float biasL[2 * ML];
  int bid = blockIdx.x;
  int qt = bid & 7;
  int bh = bid >> 3;
  int b = bh >> 4, h = bh & 15;
  int q0 = qt * 128;
  int t = threadIdx.x;
  int wv = t >> 6, lane = t & 63;
  int g = lane >> 4, r16 = lane & 15;

  #pragma unroll
  for (int k = 0; k < 8; ++k)
    biasL[t + k * 256] = bt[(size_t)(t + k * 256) * NH + h];

  short8 qhi[2][4], qlo[2][4];
  #pragma unroll
  for (int cc = 0; cc < 2; ++cc) {
    int qrow = q0 + wv * 32 + cc * 16 + r16;
    #pragma unroll
    for (int c = 0; c < 4; ++c) {
      if (c < 2) {
        size_t off = (size_t)(b * SB + qrow) * 1024 + h * DH + c * 32 + g * 8;
        qhi[cc][c] = *(const short8*)(QHg + off);
        qlo[cc][c] = *(const short8*)(QLg + off);
      } else {
        size_t off = (size_t)qrow * 1024 + h * DH + (c - 2) * 32 + g * 8;
        qhi[cc][c] = *(const short8*)(pQH + off);
        qlo[cc][c] = *(const short8*)(pQL + off);
      }
    }
  }
  __syncthreads();

  f32x4 O[2][4];
  #pragma unroll
  for (int cc = 0; cc < 2; ++cc)
    #pragma unroll
    for (int dt = 0; dt < 4; ++dt) O[cc][dt] = (f32x4){0.f, 0.f, 0.f, 0.f};
  float m_run[2][4], l_run[2][4];
  #pragma unroll
  for (int cc = 0; cc < 2; ++cc)
    #pragma unroll
    for (int reg = 0; reg < 4; ++reg) { m_run[cc][reg] = -3e38f; l_run[cc][reg] = 0.f; }

  int qb0 = q0 + wv * 32 + g * 4;
  const u16* ktH = KtfH + (size_t)(bh * 64) * 1024 + lane * 8;
  const u16* ktL = KtfL + (size_t)(bh * 64) * 1024 + lane * 8;
  const u16* kpH = KpfH + (size_t)(h * 64) * 1024 + lane * 8;
  const u16* kpL = KpfL + (size_t)(h * 64) * 1024 + lane * 8;
  const u16* vp  = Vf + (size_t)(bh * 32) * 2048 + lane * 8;
  int bb = ML + r16 - qb0;

  for (int ktr = 0; ktr < 16; ++ktr) {
    float bias[2][4][4];
    #pragma unroll
    for (int nt = 0; nt < 4; ++nt)
      #pragma unroll
      for (int reg = 0; reg < 4; ++reg) {
        bias[0][nt][reg] = biasL[bb + nt * 16 - reg];
        bias[1][nt][reg] = biasL[bb - 16 + nt * 16 - reg];
      }

    f32x4 S[2][4];
    #pragma unroll
    for (int nt = 0; nt < 4; ++nt) {
      f32x4 a0 = (f32x4){0.f, 0.f, 0.f, 0.f};
      f32x4 a1 = (f32x4){0.f, 0.f, 0.f, 0.f};
      #pragma unroll
      for (int c = 0; c < 4; ++c) {
        const u16* ph = (c < 2) ? ktH : kpH;
        const u16* pl = (c < 2) ? ktL : kpL;
        int co = (c < 2) ? c : (c - 2);
        short8 bhi = *(const short8*)(ph + nt * 1024 + co * 512);
        short8 blo = *(const short8*)(pl + nt * 1024 + co * 512);
        a0 = __builtin_amdgcn_mfma_f32_16x16x32_bf16(qhi[0][c], bhi, a0, 0, 0, 0);
        a1 = __builtin_amdgcn_mfma_f32_16x16x32_bf16(qhi[1][c], bhi, a1, 0, 0, 0);
        a0 = __builtin_amdgcn_mfma_f32_16x16x32_bf16(qlo[0][c], bhi, a0, 0, 0, 0);
        a1 = __builtin_amdgcn_mfma_f32_16x16x32_bf16(qlo[1][c], bhi, a1, 0, 0, 0);
        a0 = __builtin_amdgcn_mfma_f32_16x16x32_bf16(qhi[0][c], blo, a0, 0, 0, 0);
        a1 = __builtin_amdgcn_mfma_f32_16x16x32_bf16(qhi[1][c], blo, a1, 0, 0, 0);
      }
      S[0][nt] = a0; S[1][nt] = a1;
    }

    short8 vfrag[2][4];
    #pragma unroll
    for (int kc = 0; kc < 2; ++kc)
      #pragma unroll
      for (int dt = 0; dt < 4; ++dt)
        vfrag[kc][dt] = *(const short8*)(vp + (kc * 4 + dt) * 512);

    #pragma unroll
    for (int cc = 0; cc < 2; ++cc)
      #pragma unroll
      for (int nt = 0; nt < 4; ++nt)
        #pragma unroll
        for (int reg = 0; reg < 4; ++reg)
          S[cc][nt][reg] += bias[cc][nt][reg];

    float tm[2][4], al[2][4];
    #pragma unroll
    for (int cc = 0; cc < 2; ++cc)
      #pragma unroll
      for (int reg = 0; reg < 4; ++reg)
        tm[cc][reg] = fmaxf(fmaxf(S[cc][0][reg], S[cc][1][reg]),
                            fmaxf(S[cc][2][reg], S[cc][3][reg]));
    #pragma unroll
    for (int off = 1; off < 16; off <<= 1)
      #pragma unroll
      for (int cc = 0; cc < 2; ++cc)
        #pragma unroll
        for (int reg = 0; reg < 4; ++reg)
          tm[cc][reg] = fmaxf(tm[cc][reg], __shfl_xor(tm[cc][reg], off, 64));
    #pragma unroll
    for (int cc = 0; cc < 2; ++cc)
      #pragma unroll
      for (int reg = 0; reg < 4; ++reg) {
        float mn = fmaxf(m_run[cc][reg], tm[cc][reg]);
        al[cc][reg] = __expf(m_run[cc][reg] - mn);
        m_run[cc][reg] = mn;
      }
    float ts[2][4] = {{0.f, 0.f, 0.f, 0.f}, {0.f, 0.f, 0.f, 0.f}};
    #pragma unroll
    for (int cc = 0; cc < 2; ++cc)
      #pragma unroll
      for (int nt = 0; nt < 4; ++nt)
        #pragma unroll
        for (int reg = 0; reg < 4; ++reg) {
          float p = __expf(S[cc][nt][reg] - m_run[cc][reg]);
          S[cc][nt][reg] = p;
          ts[cc][reg] += p;
        }
    #pragma unroll
    for (int cc = 0; cc < 2; ++cc)
      #pragma unroll
      for (int reg = 0; reg < 4; ++reg)
        l_run[cc][reg] = l_run[cc][reg] * al[cc][reg] + ts[cc][reg];
    #pragma unroll
    for (int cc = 0; cc < 2; ++cc)
      #pragma unroll
      for (int dt = 0; dt < 4; ++dt)
        #pragma unroll
        for (int reg = 0; reg < 4; ++reg)
          O[cc][dt][reg] *= al[cc][reg];

    #pragma unroll
    for (int cc = 0; cc < 2; ++cc) {
      u16* pb = Pb[wv][cc];
      #pragma unroll
      for (int nt = 0; nt < 4; ++nt)
        #pragma unroll
        for (int reg = 0; reg < 4; ++reg)
          pb[(g * 4 + reg) * 72 + nt * 16 + r16] = f2bf(S[cc][nt][reg]);
    }

    #pragma unroll
    for (int kc = 0; kc < 2; ++kc) {
      #pragma unroll
      for (int cc = 0; cc < 2; ++cc) {
        short8 pa = *(const short8*)&Pb[wv][cc][r16 * 72 + kc * 32 + g * 8];
        #pragma unroll
        for (int dt = 0; dt < 4; ++dt)
          O[cc][dt] = __builtin_amdgcn_mfma_f32_16x16x32_bf16(pa, vfrag[kc][dt], O[cc][dt], 0, 0, 0);
      }
    }

    ktH += 4096; ktL += 4096; kpH += 4096; kpL += 4096;
    vp += 4096; bb += 64;
  }

  #pragma unroll
  for (int off = 1; off < 16; off <<= 1)
    #pragma unroll
    for (int cc = 0; cc < 2; ++cc)
      #pragma unroll
      for (int reg = 0; reg < 4; ++reg)
        l_run[cc][reg] += __shfl_xor(l_run[cc][reg], off, 64);
  #pragma unroll
  for (int cc = 0; cc < 2; ++cc)
    #pragma unroll
    for (int reg = 0; reg < 4; ++reg) l_run[cc][reg] = 1.0f / l_run[cc][reg];
  #pragma unroll
  for (int cc = 0; cc < 2; ++cc)
    #pragma unroll
    for (int dt = 0; dt < 4; ++dt)
      #pragma unroll
      for (int reg = 0; reg < 4; ++reg)
        out[(size_t)(b * SB + qb0 + cc * 16 + reg) * DM + h * DH + dt * 16 + r16] =
            O[cc][dt][reg] * l_run[cc][reg];
}

extern "C" void kernel_launch(void* const* d_in, const int* in_sizes, int n_in,
                              void* d_out, int out_size, void* d_ws, size_t ws_size,
                              hipStream_t stream) {
  const float* x     = (const float*)d_in[0];
  const float* gamma = (const float*)d_in[1];
  const float* beta  = (const float*)d_in[2];
  const float* w_pos = (const float*)d_in[3];
  const float* w_tok = (const float*)d_in[4];
  const float* bt    = (const float*)d_in[5];
  float* out = (float*)d_out;
  float* ws  = (float*)d_ws;
  const unsigned M1 = 1u << 20;
  const float IS = 11.313708498984761f;  // sqrt(2*dh)

  // Workspace (f32 units, 17M = 68 MB, NO overlays — all buffers disjoint):
  _Float16* peH   = (_Float16*)(ws);                  // [0, 0.5M)
  _Float16* peL   = (_Float16*)(ws + M1 / 2);         // [0.5M, 1M)
  _Float16* xnH   = (_Float16*)(ws + 1 * M1);         // [1M, 3M)
  _Float16* xnL   = (_Float16*)(ws + 3 * M1);         // [3M, 5M)
  u16*      KpfH  = (u16*)(ws + 5 * M1);              // [5M, 5.5M)
  u16*      KpfL  = (u16*)(ws + 5 * M1 + M1 / 2);     // [5.5M, 6M)
  u16*      posQH = (u16*)(ws + 6 * M1);              // [6M, 6.5M)
  u16*      posQL = (u16*)(ws + 6 * M1 + M1 / 2);     // [6.5M, 7M)
  u16*      KtfH  = (u16*)(ws + 7 * M1);              // [7M, 9M)
  u16*      KtfL  = (u16*)(ws + 9 * M1);              // [9M, 11M)
  u16*      QH    = (u16*)(ws + 11 * M1);             // [11M, 13M)
  u16*      QL    = (u16*)(ws + 13 * M1);             // [13M, 15M)
  u16*      Vf    = (u16*)(ws + 15 * M1);             // [15M, 17M)

  // S1: pe-pack (64 blocks) + LN-pack (256 blocks)
  prep_all<<<320, 256, 0, stream>>>(x, gamma, beta, peH, peL, xnH, xnL);
  // S2: merged GEMM — tok blocks 0..383 (xn @ w_tok^T), pos blocks 384..447
  //     (pe @ w_pos^T), B staged from fp32 originals, pos hidden in tok's shadow
  gemm16m<<<448, 256, 0, stream>>>(
      xnH, xnL, peH, peL, w_tok, w_pos,
      KtfH, KtfL, KpfH, KpfL, QH, QL, posQH, posQL, Vf,
      1.0f / 32.0f, IS / 32.0f, 1.0f / 32.0f);
  // S3: attention
  attn_mfma9<<<BB * NH * (SB / 128), 256, 0, stream>>>(
      KtfH, KtfL, KpfH, KpfL, QH, QL, posQH, posQL, Vf, bt, out);
}

// Round 13
// 259.623 us; speedup vs baseline: 1.8916x; 1.2111x over previous
//
#include <hip/hip_runtime.h>
#include <math.h>

#define SB 1024   // seq len
#define DM 1024   // d_model
#define BB 4      // batch
#define NH 16     // heads
#define DH 64     // head dim
#define ML 1024   // MAX_LEN

typedef __attribute__((ext_vector_type(8))) short short8;
typedef __attribute__((ext_vector_type(8))) _Float16 half8;
typedef __attribute__((ext_vector_type(4))) float f32x4;
typedef unsigned short u16;

__device__ __forceinline__ u16 f2bf(float x) {
  unsigned u = __float_as_uint(x);
  u += 0x7fffu + ((u >> 16) & 1u);
  return (u16)(u >> 16);
}
__device__ __forceinline__ float bf2f(u16 h) { return __uint_as_float((unsigned)h << 16); }

// async global->LDS, 16B per lane; lds base must be wave-uniform (HW adds lane*16)
__device__ __forceinline__ void async16(void* lds, const void* g) {
  __builtin_amdgcn_global_load_lds(
      (const __attribute__((address_space(1))) unsigned*)g,
      (__attribute__((address_space(3))) unsigned*)lds, 16, 0, 0);
}

// ======== S1: fused prep (pe | LN | optional weight packs) ========

__device__ __forceinline__ void pack16_body(int rt, int t, const float* __restrict__ src,
    _Float16* __restrict__ dH, _Float16* __restrict__ dL, float scale) {
  int r16 = t >> 4, ks = t & 15;
  const float* sp = src + (size_t)(rt * 16 + r16) * 1024 + ks * 64;
  float v[64];
  #pragma unroll
  for (int i = 0; i < 16; ++i) {
    float4 f = *(const float4*)(sp + i * 4);
    v[i*4+0] = f.x; v[i*4+1] = f.y; v[i*4+2] = f.z; v[i*4+3] = f.w;
  }
  #pragma unroll
  for (int hf = 0; hf < 2; ++hf) {
    int kt = ks * 2 + hf;
    #pragma unroll
    for (int gg = 0; gg < 4; ++gg) {
      half8 hv, lv;
      #pragma unroll
      for (int j = 0; j < 8; ++j) {
        float x = v[hf * 32 + gg * 8 + j] * scale;
        _Float16 h = (_Float16)x;
        hv[j] = h;
        lv[j] = (_Float16)(x - (float)h);
      }
      size_t off = ((size_t)(rt * 32 + kt) * 64 + r16 + gg * 16) * 8;
      *(half8*)(dH + off) = hv;
      *(half8*)(dL + off) = lv;
    }
  }
}

__device__ __forceinline__ void pe_pack_body(int rt, int t,
    _Float16* __restrict__ dH, _Float16* __restrict__ dL) {
  int r16 = t >> 4, ks = t & 15;
  int p = rt * 16 + r16;
  float v[64];
  #pragma unroll
  for (int i = 0; i < 32; ++i) {
    int c0 = ks * 64 + 2 * i;
    float div = expf((float)c0 * (-9.210340371976184f / (float)DM));
    float ang = (float)p * div;
    v[2*i]   = sinf(ang);
    v[2*i+1] = cosf(ang);
  }
  #pragma unroll
  for (int hf = 0; hf < 2; ++hf) {
    int kt = ks * 2 + hf;
    #pragma unroll
    for (int gg = 0; gg < 4; ++gg) {
      half8 hv, lv;
      #pragma unroll
      for (int j = 0; j < 8; ++j) {
        float x = v[hf * 32 + gg * 8 + j];
        _Float16 h = (_Float16)x;
        hv[j] = h;
        lv[j] = (_Float16)(x - (float)h);
      }
      size_t off = ((size_t)(rt * 32 + kt) * 64 + r16 + gg * 16) * 8;
      *(half8*)(dH + off) = hv;
      *(half8*)(dL + off) = lv;
    }
  }
}

__device__ __forceinline__ void ln_pack_body(int rt, int t, const float* __restrict__ x,
    const float* __restrict__ gamma, const float* __restrict__ beta,
    _Float16* __restrict__ dH, _Float16* __restrict__ dL) {
  int r16 = t >> 4, ks = t & 15;
  const float* sp = x + (size_t)(rt * 16 + r16) * 1024 + ks * 64;
  float v[64];
  float s1 = 0.f, s2 = 0.f;
  #pragma unroll
  for (int i = 0; i < 16; ++i) {
    float4 f = *(const float4*)(sp + i * 4);
    v[i*4+0] = f.x; v[i*4+1] = f.y; v[i*4+2] = f.z; v[i*4+3] = f.w;
    s1 += f.x + f.y + f.z + f.w;
    s2 += f.x*f.x + f.y*f.y + f.z*f.z + f.w*f.w;
  }
  #pragma unroll
  for (int off = 1; off < 16; off <<= 1) {
    s1 += __shfl_xor(s1, off, 64);
    s2 += __shfl_xor(s2, off, 64);
  }
  float mu = s1 * (1.0f / 1024.0f);
  float var = s2 * (1.0f / 1024.0f) - mu * mu;
  float rstd = rsqrtf(var + 1e-5f);
  #pragma unroll
  for (int hf = 0; hf < 2; ++hf) {
    int kt = ks * 2 + hf;
    #pragma unroll
    for (int gg = 0; gg < 4; ++gg) {
      const float* gp = gamma + ks * 64 + hf * 32 + gg * 8;
      const float* bp = beta  + ks * 64 + hf * 32 + gg * 8;
      half8 hv, lv;
      #pragma unroll
      for (int j = 0; j < 8; ++j) {
        float xn = (v[hf * 32 + gg * 8 + j] - mu) * rstd * gp[j] + bp[j];
        _Float16 h = (_Float16)xn;
        hv[j] = h;
        lv[j] = (_Float16)(xn - (float)h);
      }
      size_t off = ((size_t)(rt * 32 + kt) * 64 + r16 + gg * 16) * 8;
      *(half8*)(dH + off) = hv;
      *(half8*)(dL + off) = lv;
    }
  }
}

// launch with 320 blocks (fallback: pe+LN) or 640 (fast: + w_pos + w_tok packs)
__global__ __launch_bounds__(256) void prep_all(
    const float* __restrict__ x, const float* __restrict__ gamma,
    const float* __restrict__ beta,
    const float* __restrict__ w_pos, const float* __restrict__ w_tok,
    _Float16* __restrict__ peH, _Float16* __restrict__ peL,
    _Float16* __restrict__ xnH, _Float16* __restrict__ xnL,
    _Float16* __restrict__ wpH, _Float16* __restrict__ wpL,
    _Float16* __restrict__ wtH, _Float16* __restrict__ wtL) {
  int bid = blockIdx.x;
  int t = threadIdx.x;
  if (bid < 64)       pe_pack_body(bid, t, peH, peL);
  else if (bid < 320) ln_pack_body(bid - 64, t, x, gamma, beta, xnH, xnL);
  else if (bid < 448) pack16_body(bid - 320, t, w_pos, wpH, wpL, 32.0f);
  else                pack16_body(bid - 448, t, w_tok, wtH, wtL, 32.0f);
}

// ======== S2-fast: MERGED GEMM from prepacked planes (r11 staging, r12 grid) ========
// tok blocks 0..383, pos 384..447. A + Bhi via async16, Blo direct frag loads.
// Epilogue writes final attn layouts (verified r11/r12).
#define GBM 128
#define GBN 256

__global__ __launch_bounds__(256, 2) void gemm16p(
    const _Float16* __restrict__ AtH, const _Float16* __restrict__ AtL,
    const _Float16* __restrict__ ApH, const _Float16* __restrict__ ApL,
    const _Float16* __restrict__ BtH, const _Float16* __restrict__ BtL,
    const _Float16* __restrict__ BpH, const _Float16* __restrict__ BpL,
    u16* __restrict__ KtfH, u16* __restrict__ KtfL,
    u16* __restrict__ KpfH, u16* __restrict__ KpfL,
    u16* __restrict__ QH, u16* __restrict__ QL,
    u16* __restrict__ pQH, u16* __restrict__ pQL,
    u16* __restrict__ vF, float sK, float sQ, float sV) {
  __shared__ _Float16 L[32 * 512];
  int t = threadIdx.x;
  int wv = t >> 6, lane = t & 63;
  int wm = wv >> 1, wn = wv & 1;
  int r16 = lane & 15, g = lane >> 4;

  int bid = blockIdx.x;
  bool isPos = (bid >= 384);
  int idx = isPos ? bid - 384 : bid;
  int n0, m0;
  const _Float16 *AH, *AL, *BH, *BL;
  if (isPos) { n0 = (idx & 7) * 256;  m0 = (idx >> 3) * 128;
               AH = ApH; AL = ApL; BH = BpH; BL = BpL; }
  else       { n0 = (idx % 12) * 256; m0 = (idx / 12) * 128;
               AH = AtH; AL = AtL; BH = BtH; BL = BtL; }
  int mt0 = m0 >> 4, nt0 = n0 >> 4;
  bool split = isPos || (n0 < 2048);   // tok V band (n0>=2048): hh-only

  f32x4 acc[4][8];
  #pragma unroll
  for (int i = 0; i < 4; ++i)
    #pragma unroll
    for (int j = 0; j < 8; ++j) acc[i][j] = (f32x4){0.f, 0.f, 0.f, 0.f};

  for (int kt = 0; kt < 32; ++kt) {
    __syncthreads();
    #pragma unroll
    for (int rd = 0; rd < 8; ++rd) {
      int ci = rd * 4 + wv;
      bool isAlo = (ci < 16) && (ci & 1);
      if (!split && isAlo) continue;         // wave-uniform skip
      const _Float16* src;
      if (ci < 16) {
        int mt = ci >> 1, pl = ci & 1;
        const _Float16* P = pl ? AL : AH;
        src = P + ((size_t)((mt0 + mt) * 32 + kt) * 64 + lane) * 8;
      } else {
        int nt = ci - 16;
        src = BH + ((size_t)((nt0 + nt) * 32 + kt) * 64 + lane) * 8;
      }
      async16(&L[ci * 512], src);
    }
    half8 blo[8];
    if (split) {
      #pragma unroll
      for (int j = 0; j < 8; ++j) {
        int ntg = nt0 + wn * 8 + j;
        blo[j] = *(const half8*)(BL + ((size_t)(ntg * 32 + kt) * 64 + lane) * 8);
      }
    }
    __syncthreads();

    half8 ah[4], al[4];
    #pragma unroll
    for (int i = 0; i < 4; ++i)
      ah[i] = *(const half8*)&L[(((wm * 4 + i) * 2 + 0) * 512) + lane * 8];
    if (split) {
      #pragma unroll
      for (int i = 0; i < 4; ++i)
        al[i] = *(const half8*)&L[(((wm * 4 + i) * 2 + 1) * 512) + lane * 8];
    }
    #pragma unroll
    for (int j = 0; j < 8; ++j) {
      half8 bh = *(const half8*)&L[((16 + wn * 8 + j) * 512) + lane * 8];
      #pragma unroll
      for (int i = 0; i < 4; ++i) {
        acc[i][j] = __builtin_amdgcn_mfma_f32_16x16x32_f16(ah[i], bh, acc[i][j], 0, 0, 0);
        if (split) {
          acc[i][j] = __builtin_amdgcn_mfma_f32_16x16x32_f16(al[i], bh, acc[i][j], 0, 0, 0);
          acc[i][j] = __builtin_amdgcn_mfma_f32_16x16x32_f16(ah[i], blo[j], acc[i][j], 0, 0, 0);
        }
      }
    }
  }

  int band = n0 >> 10;
  u16* fKH = isPos ? KpfH : KtfH;
  u16* fKL = isPos ? KpfL : KtfL;
  u16* qHo = isPos ? pQH  : QH;
  u16* qLo = isPos ? pQL  : QL;
  if (band == 1) {
    #pragma unroll
    for (int i = 0; i < 4; ++i)
      #pragma unroll
      for (int j = 0; j < 8; ++j) {
        int lc = (n0 & 1023) + wn * 128 + j * 16 + r16;
        #pragma unroll
        for (int reg = 0; reg < 4; ++reg) {
          int row = m0 + wm * 64 + i * 16 + g * 4 + reg;
          float cv = acc[i][j][reg] * sQ;
          u16 hi = f2bf(cv);
          qHo[(size_t)row * 1024 + lc] = hi;
          qLo[(size_t)row * 1024 + lc] = f2bf(cv - bf2f(hi));
        }
      }
  } else if (band == 0) {
    #pragma unroll
    for (int i = 0; i < 4; ++i)
      #pragma unroll
      for (int j = 0; j < 8; ++j) {
        int colg = n0 + wn * 128 + j * 16 + r16;   // < 1024
        int h = colg >> 6, dc = colg & 63;
        #pragma unroll
        for (int reg = 0; reg < 4; ++reg) {
          int row = m0 + wm * 64 + i * 16 + g * 4 + reg;
          int bhK = (row >> 10) * NH + h;
          size_t a = ((size_t)((bhK * 64 + ((row & 1023) >> 4)) * 2 + (dc >> 5)) << 9)
                   + ((row & 15) + 16 * ((dc >> 3) & 3)) * 8 + (dc & 7);
          float cv = acc[i][j][reg] * sK;
          u16 hi = f2bf(cv);
          fKH[a] = hi;
          fKL[a] = f2bf(cv - bf2f(hi));
        }
      }
  } else {
    #pragma unroll
    for (int i = 0; i < 4; ++i)
      #pragma unroll
      for (int j = 0; j < 8; ++j) {
        int colg = (n0 & 1023) + wn * 128 + j * 16 + r16;
        int h = colg >> 6, dc = colg & 63;
        #pragma unroll
        for (int reg = 0; reg < 4; ++reg) {
          int row = m0 + wm * 64 + i * 16 + g * 4 + reg;
          int s = row & 1023;
          size_t a = ((size_t)((((row >> 10) * NH + h) * 32 + (s >> 5)) * 4 + (dc >> 4)) << 9)
                   + ((s >> 3) & 3) * 128 + (s & 7) + (dc & 15) * 8;
          vF[a] = f2bf(acc[i][j][reg] * sV);
        }
      }
  }
}

// ======== S2-fallback: r12 merged GEMM, B staged from fp32 originals ========
__global__ __launch_bounds__(256, 2) void gemm16m(
    const _Float16* __restrict__ AtH, const _Float16* __restrict__ AtL,
    const _Float16* __restrict__ ApH, const _Float16* __restrict__ ApL,
    const float* __restrict__ Wt, const float* __restrict__ Wp,
    u16* __restrict__ KtfH, u16* __restrict__ KtfL,
    u16* __restrict__ KpfH, u16* __restrict__ KpfL,
    u16* __restrict__ QH, u16* __restrict__ QL,
    u16* __restrict__ pQH, u16* __restrict__ pQL,
    u16* __restrict__ vF, float sK, float sQ, float sV) {
  __shared__ _Float16 L[48 * 512];
  int t = threadIdx.x;
  int wv = t >> 6, lane = t & 63;
  int wm = wv >> 1, wn = wv & 1;
  int r16 = lane & 15, g = lane >> 4;

  int bid = blockIdx.x;
  bool isPos = (bid >= 384);
  int idx = isPos ? bid - 384 : bid;
  int n0, m0;
  const _Float16 *AH, *AL;
  const float* W;
  if (isPos) { n0 = (idx & 7) * 256;  m0 = (idx >> 3) * 128; AH = ApH; AL = ApL; W = Wp; }
  else       { n0 = (idx % 12) * 256; m0 = (idx / 12) * 128; AH = AtH; AL = AtL; W = Wt; }
  int mt0 = m0 >> 4, nt0 = n0 >> 4;
  bool split = isPos || (n0 < 2048);

  f32x4 acc[4][8];
  #pragma unroll
  for (int i = 0; i < 4; ++i)
    #pragma unroll
    for (int j = 0; j < 8; ++j) acc[i][j] = (f32x4){0.f, 0.f, 0.f, 0.f};

  for (int kt = 0; kt < 32; ++kt) {
    __syncthreads();
    #pragma unroll
    for (int rd = 0; rd < 4; ++rd) {
      int ci = rd * 4 + wv;
      int mt = ci >> 1, pl = ci & 1;
      if (!split && pl) continue;
      const _Float16* src = (pl ? AL : AH)
          + ((size_t)((mt0 + mt) * 32 + kt) * 64 + lane) * 8;
      async16(&L[ci * 512], src);
    }
    #pragma unroll
    for (int tt = 0; tt < 4; ++tt) {
      int nt = wv * 4 + tt;
      const float* wsrc = W + (size_t)((nt0 + nt) * 16 + r16) * 1024 + kt * 32 + g * 8;
      float4 w0 = *(const float4*)wsrc;
      float4 w1 = *(const float4*)(wsrc + 4);
      float wvv[8] = {w0.x, w0.y, w0.z, w0.w, w1.x, w1.y, w1.z, w1.w};
      half8 hv, lv;
      #pragma unroll
      for (int j = 0; j < 8; ++j) {
        float xx = wvv[j] * 32.0f;
        _Float16 h = (_Float16)xx;
        hv[j] = h;
        lv[j] = (_Float16)(xx - (float)h);
      }
      *(half8*)&L[(16 + nt) * 512 + lane * 8] = hv;
      if (split) *(half8*)&L[(32 + nt) * 512 + lane * 8] = lv;
    }
    __syncthreads();

    half8 ah[4], al[4];
    #pragma unroll
    for (int i = 0; i < 4; ++i)
      ah[i] = *(const half8*)&L[(((wm * 4 + i) * 2 + 0) * 512) + lane * 8];
    if (split) {
      #pragma unroll
      for (int i = 0; i < 4; ++i)
        al[i] = *(const half8*)&L[(((wm * 4 + i) * 2 + 1) * 512) + lane * 8];
    }
    #pragma unroll
    for (int j = 0; j < 8; ++j) {
      half8 bh = *(const half8*)&L[((16 + wn * 8 + j) * 512) + lane * 8];
      #pragma unroll
      for (int i = 0; i < 4; ++i) {
        acc[i][j] = __builtin_amdgcn_mfma_f32_16x16x32_f16(ah[i], bh, acc[i][j], 0, 0, 0);
        if (split) {
          half8 bl = *(const half8*)&L[((32 + wn * 8 + j) * 512) + lane * 8];
          acc[i][j] = __builtin_amdgcn_mfma_f32_16x16x32_f16(al[i], bh, acc[i][j], 0, 0, 0);
          acc[i][j] = __builtin_amdgcn_mfma_f32_16x16x32_f16(ah[i], bl, acc[i][j], 0, 0, 0);
        }
      }
    }
  }

  int band = n0 >> 10;
  u16* fKH = isPos ? KpfH : KtfH;
  u16* fKL = isPos ? KpfL : KtfL;
  u16* qHo = isPos ? pQH  : QH;
  u16* qLo = isPos ? pQL  : QL;
  if (band == 1) {
    #pragma unroll
    for (int i = 0; i < 4; ++i)
      #pragma unroll
      for (int j = 0; j < 8; ++j) {
        int lc = (n0 & 1023) + wn * 128 + j * 16 + r16;
        #pragma unroll
        for (int reg = 0; reg < 4; ++reg) {
          int row = m0 + wm * 64 + i * 16 + g * 4 + reg;
          float cv = acc[i][j][reg] * sQ;
          u16 hi = f2bf(cv);
          qHo[(size_t)row * 1024 + lc] = hi;
          qLo[(size_t)row * 1024 + lc] = f2bf(cv - bf2f(hi));
        }
      }
  } else if (band == 0) {
    #pragma unroll
    for (int i = 0; i < 4; ++i)
      #pragma unroll
      for (int j = 0; j < 8; ++j) {
        int colg = n0 + wn * 128 + j * 16 + r16;
        int h = colg >> 6, dc = colg & 63;
        #pragma unroll
        for (int reg = 0; reg < 4; ++reg) {
          int row = m0 + wm * 64 + i * 16 + g * 4 + reg;
          int bhK = (row >> 10) * NH + h;
          size_t a = ((size_t)((bhK * 64 + ((row & 1023) >> 4)) * 2 + (dc >> 5)) << 9)
                   + ((row & 15) + 16 * ((dc >> 3) & 3)) * 8 + (dc & 7);
          float cv = acc[i][j][reg] * sK;
          u16 hi = f2bf(cv);
          fKH[a] = hi;
          fKL[a] = f2bf(cv - bf2f(hi));
        }
      }
  } else {
    #pragma unroll
    for (int i = 0; i < 4; ++i)
      #pragma unroll
      for (int j = 0; j < 8; ++j) {
        int colg = (n0 & 1023) + wn * 128 + j * 16 + r16;
        int h = colg >> 6, dc = colg & 63;
        #pragma unroll
        for (int reg = 0; reg < 4; ++reg) {
          int row = m0 + wm * 64 + i * 16 + g * 4 + reg;
          int s = row & 1023;
          size_t a = ((size_t)((((row >> 10) * NH + h) * 32 + (s >> 5)) * 4 + (dc >> 4)) << 9)
                   + ((s >> 3) & 3) * 128 + (s & 7) + (dc & 15) * 8;
          vF[a] = f2bf(acc[i][j][reg] * sV);
        }
      }
  }
}

// ======== S3: MFMA flash attention (r11 verbatim — verified) ========
__global__ __launch_bounds__(256, 2) void attn_mfma9(
    const u16* __restrict__ KtfH, const u16* __restrict__ KtfL,
    const u16* __restrict__ KpfH, const u16* __restrict__ KpfL,
    const u16* __restrict__ QHg, const u16* __restrict__ QLg,
    const u16* __restrict__ pQH, const u16* __restrict__ pQL,
    const u16* __restrict__ Vf,
    const float* __restrict__ bt,
    float* __restrict__ out) {
  __shared__ u16 Pb[4][2][16 * 72];
  __shared__ float biasL[2 * ML];
  int bid = blockIdx.x;
  int qt = bid & 7;
  int bh = bid >> 3;
  int b = bh >> 4, h = bh & 15;
  int q0 = qt * 128;
  int t = threadIdx.x;
  int wv = t >> 6, lane = t & 63;
  int g = lane >> 4, r16 = lane & 15;

  #pragma unroll
  for (int k = 0; k < 8; ++k)
    biasL[t + k * 256] = bt[(size_t)(t + k * 256) * NH + h];

  short8 qhi[2][4], qlo[2][4];
  #pragma unroll
  for (int cc = 0; cc < 2; ++cc) {
    int qrow = q0 + wv * 32 + cc * 16 + r16;
    #pragma unroll
    for (int c = 0; c < 4; ++c) {
      if (c < 2) {
        size_t off = (size_t)(b * SB + qrow) * 1024 + h * DH + c * 32 + g * 8;
        qhi[cc][c] = *(const short8*)(QHg + off);
        qlo[cc][c] = *(const short8*)(QLg + off);
      } else {
        size_t off = (size_t)qrow * 1024 + h * DH + (c - 2) * 32 + g * 8;
        qhi[cc][c] = *(const short8*)(pQH + off);
        qlo[cc][c] = *(const short8*)(pQL + off);
      }
    }
  }
  __syncthreads();

  f32x4 O[2][4];
  #pragma unroll
  for (int cc = 0; cc < 2; ++cc)
    #pragma unroll
    for (int dt = 0; dt < 4; ++dt) O[cc][dt] = (f32x4){0.f, 0.f, 0.f, 0.f};
  float m_run[2][4], l_run[2][4];
  #pragma unroll
  for (int cc = 0; cc < 2; ++cc)
    #pragma unroll
    for (int reg = 0; reg < 4; ++reg) { m_run[cc][reg] = -3e38f; l_run[cc][reg] = 0.f; }

  int qb0 = q0 + wv * 32 + g * 4;
  const u16* ktH = KtfH + (size_t)(bh * 64) * 1024 + lane * 8;
  const u16* ktL = KtfL + (size_t)(bh * 64) * 1024 + lane * 8;
  const u16* kpH = KpfH + (size_t)(h * 64) * 1024 + lane * 8;
  const u16* kpL = KpfL + (size_t)(h * 64) * 1024 + lane * 8;
  const u16* vp  = Vf + (size_t)(bh * 32) * 2048 + lane * 8;
  int bb = ML + r16 - qb0;

  for (int ktr = 0; ktr < 16; ++ktr) {
    float bias[2][4][4];
    #pragma unroll
    for (int nt = 0; nt < 4; ++nt)
      #pragma unroll
      for (int reg = 0; reg < 4; ++reg) {
        bias[0][nt][reg] = biasL[bb + nt * 16 - reg];
        bias[1][nt][reg] = biasL[bb - 16 + nt * 16 - reg];
      }

    f32x4 S[2][4];
    #pragma unroll
    for (int nt = 0; nt < 4; ++nt) {
      f32x4 a0 = (f32x4){0.f, 0.f, 0.f, 0.f};
      f32x4 a1 = (f32x4){0.f, 0.f, 0.f, 0.f};
      #pragma unroll
      for (int c = 0; c < 4; ++c) {
        const u16* ph = (c < 2) ? ktH : kpH;
        const u16* pl = (c < 2) ? ktL : kpL;
        int co = (c < 2) ? c : (c - 2);
        short8 bhi = *(const short8*)(ph + nt * 1024 + co * 512);
        short8 blo = *(const short8*)(pl + nt * 1024 + co * 512);
        a0 = __builtin_amdgcn_mfma_f32_16x16x32_bf16(qhi[0][c], bhi, a0, 0, 0, 0);
        a1 = __builtin_amdgcn_mfma_f32_16x16x32_bf16(qhi[1][c], bhi, a1, 0, 0, 0);
        a0 = __builtin_amdgcn_mfma_f32_16x16x32_bf16(qlo[0][c], bhi, a0, 0, 0, 0);
        a1 = __builtin_amdgcn_mfma_f32_16x16x32_bf16(qlo[1][c], bhi, a1, 0, 0, 0);
        a0 = __builtin_amdgcn_mfma_f32_16x16x32_bf16(qhi[0][c], blo, a0, 0, 0, 0);
        a1 = __builtin_amdgcn_mfma_f32_16x16x32_bf16(qhi[1][c], blo, a1, 0, 0, 0);
      }
      S[0][nt] = a0; S[1][nt] = a1;
    }

    short8 vfrag[2][4];
    #pragma unroll
    for (int kc = 0; kc < 2; ++kc)
      #pragma unroll
      for (int dt = 0; dt < 4; ++dt)
        vfrag[kc][dt] = *(const short8*)(vp + (kc * 4 + dt) * 512);

    #pragma unroll
    for (int cc = 0; cc < 2; ++cc)
      #pragma unroll
      for (int nt = 0; nt < 4; ++nt)
        #pragma unroll
        for (int reg = 0; reg < 4; ++reg)
          S[cc][nt][reg] += bias[cc][nt][reg];

    float tm[2][4], al[2][4];
    #pragma unroll
    for (int cc = 0; cc < 2; ++cc)
      #pragma unroll
      for (int reg = 0; reg < 4; ++reg)
        tm[cc][reg] = fmaxf(fmaxf(S[cc][0][reg], S[cc][1][reg]),
                            fmaxf(S[cc][2][reg], S[cc][3][reg]));
    #pragma unroll
    for (int off = 1; off < 16; off <<= 1)
      #pragma unroll
      for (int cc = 0; cc < 2; ++cc)
        #pragma unroll
        for (int reg = 0; reg < 4; ++reg)
          tm[cc][reg] = fmaxf(tm[cc][reg], __shfl_xor(tm[cc][reg], off, 64));
    #pragma unroll
    for (int cc = 0; cc < 2; ++cc)
      #pragma unroll
      for (int reg = 0; reg < 4; ++reg) {
        float mn = fmaxf(m_run[cc][reg], tm[cc][reg]);
        al[cc][reg] = __expf(m_run[cc][reg] - mn);
        m_run[cc][reg] = mn;
      }
    float ts[2][4] = {{0.f, 0.f, 0.f, 0.f}, {0.f, 0.f, 0.f, 0.f}};
    #pragma unroll
    for (int cc = 0; cc < 2; ++cc)
      #pragma unroll
      for (int nt = 0; nt < 4; ++nt)
        #pragma unroll
        for (int reg = 0; reg < 4; ++reg) {
          float p = __expf(S[cc][nt][reg] - m_run[cc][reg]);
          S[cc][nt][reg] = p;
          ts[cc][reg] += p;
        }
    #pragma unroll
    for (int cc = 0; cc < 2; ++cc)
      #pragma unroll
      for (int reg = 0; reg < 4; ++reg)
        l_run[cc][reg] = l_run[cc][reg] * al[cc][reg] + ts[cc][reg];
    #pragma unroll
    for (int cc = 0; cc < 2; ++cc)
      #pragma unroll
      for (int dt = 0; dt < 4; ++dt)
        #pragma unroll
        for (int reg = 0; reg < 4; ++reg)
          O[cc][dt][reg] *= al[cc][reg];

    #pragma unroll
    for (int cc = 0; cc < 2; ++cc) {
      u16* pb = Pb[wv][cc];
      #pragma unroll
      for (int nt = 0; nt < 4; ++nt)
        #pragma unroll
        for (int reg = 0; reg < 4; ++reg)
          pb[(g * 4 + reg) * 72 + nt * 16 + r16] = f2bf(S[cc][nt][reg]);
    }

    #pragma unroll
    for (int kc = 0; kc < 2; ++kc) {
      #pragma unroll
      for (int cc = 0; cc < 2; ++cc) {
        short8 pa = *(const short8*)&Pb[wv][cc][r16 * 72 + kc * 32 + g * 8];
        #pragma unroll
        for (int dt = 0; dt < 4; ++dt)
          O[cc][dt] = __builtin_amdgcn_mfma_f32_16x16x32_bf16(pa, vfrag[kc][dt], O[cc][dt], 0, 0, 0);
      }
    }

    ktH += 4096; ktL += 4096; kpH += 4096; kpL += 4096;
    vp += 4096; bb += 64;
  }

  #pragma unroll
  for (int off = 1; off < 16; off <<= 1)
    #pragma unroll
    for (int cc = 0; cc < 2; ++cc)
      #pragma unroll
      for (int reg = 0; reg < 4; ++reg)
        l_run[cc][reg] += __shfl_xor(l_run[cc][reg], off, 64);
  #pragma unroll
  for (int cc = 0; cc < 2; ++cc)
    #pragma unroll
    for (int reg = 0; reg < 4; ++reg) l_run[cc][reg] = 1.0f / l_run[cc][reg];
  #pragma unroll
  for (int cc = 0; cc < 2; ++cc)
    #pragma unroll
    for (int dt = 0; dt < 4; ++dt)
      #pragma unroll
      for (int reg = 0; reg < 4; ++reg)
        out[(size_t)(b * SB + qb0 + cc * 16 + reg) * DM + h * DH + dt * 16 + r16] =
            O[cc][dt][reg] * l_run[cc][reg];
}

extern "C" void kernel_launch(void* const* d_in, const int* in_sizes, int n_in,
                              void* d_out, int out_size, void* d_ws, size_t ws_size,
                              hipStream_t stream) {
  const float* x     = (const float*)d_in[0];
  const float* gamma = (const float*)d_in[1];
  const float* beta  = (const float*)d_in[2];
  const float* w_pos = (const float*)d_in[3];
  const float* w_tok = (const float*)d_in[4];
  const float* bt    = (const float*)d_in[5];
  float* out = (float*)d_out;
  float* ws  = (float*)d_ws;
  const size_t M1 = 1u << 20;
  const float IS = 11.313708498984761f;  // sqrt(2*dh)

  u16 *KtfH, *KtfL, *KpfH, *KpfL, *QH, *QL, *posQH, *posQL, *Vf;

  if (ws_size >= 22 * M1 * 4) {
    // ---- FAST path: 88 MB, prepacked weight planes, all buffers disjoint ----
    _Float16* peH = (_Float16*)(ws);                  // [0, 0.5M)
    _Float16* peL = (_Float16*)(ws + M1 / 2);         // [0.5, 1M)
    _Float16* xnH = (_Float16*)(ws + 1 * M1);         // [1, 3M)
    _Float16* xnL = (_Float16*)(ws + 3 * M1);         // [3, 5M)
    _Float16* wpH = (_Float16*)(ws + 5 * M1);         // [5, 6M)
    _Float16* wpL = (_Float16*)(ws + 6 * M1);         // [6, 7M)
    _Float16* wtH = (_Float16*)(ws + 7 * M1);         // [7, 8.5M)
    _Float16* wtL = (_Float16*)(ws + 8 * M1 + M1/2);  // [8.5, 10M)
    KpfH  = (u16*)(ws + 10 * M1);                     // [10, 10.5M)
    KpfL  = (u16*)(ws + 10 * M1 + M1 / 2);            // [10.5, 11M)
    posQH = (u16*)(ws + 11 * M1);                     // [11, 11.5M)
    posQL = (u16*)(ws + 11 * M1 + M1 / 2);            // [11.5, 12M)
    KtfH  = (u16*)(ws + 12 * M1);                     // [12, 14M)
    KtfL  = (u16*)(ws + 14 * M1);                     // [14, 16M)
    QH    = (u16*)(ws + 16 * M1);                     // [16, 18M)
    QL    = (u16*)(ws + 18 * M1);                     // [18, 20M)
    Vf    = (u16*)(ws + 20 * M1);                     // [20, 22M)

    prep_all<<<640, 256, 0, stream>>>(x, gamma, beta, w_pos, w_tok,
        peH, peL, xnH, xnL, wpH, wpL, wtH, wtL);
    gemm16p<<<448, 256, 0, stream>>>(
        xnH, xnL, peH, peL, wtH, wtL, wpH, wpL,
        KtfH, KtfL, KpfH, KpfL, QH, QL, posQH, posQL, Vf,
        1.0f / 32.0f, IS / 32.0f, 1.0f / 32.0f);
  } else {
    // ---- FALLBACK: 68 MB, r12 path (B staged from fp32 originals) ----
    _Float16* peH = (_Float16*)(ws);                  // [0, 0.5M)
    _Float16* peL = (_Float16*)(ws + M1 / 2);         // [0.5, 1M)
    _Float16* xnH = (_Float16*)(ws + 1 * M1);         // [1, 3M)
    _Float16* xnL = (_Float16*)(ws + 3 * M1);         // [3, 5M)
    KpfH  = (u16*)(ws + 5 * M1);
    KpfL  = (u16*)(ws + 5 * M1 + M1 / 2);
    posQH = (u16*)(ws + 6 * M1);
    posQL = (u16*)(ws + 6 * M1 + M1 / 2);
    KtfH  = (u16*)(ws + 7 * M1);
    KtfL  = (u16*)(ws + 9 * M1);
    QH    = (u16*)(ws + 11 * M1);
    QL    = (u16*)(ws + 13 * M1);
    Vf    = (u16*)(ws + 15 * M1);

    prep_all<<<320, 256, 0, stream>>>(x, gamma, beta, w_pos, w_tok,
        peH, peL, xnH, xnL, (_Float16*)nullptr, (_Float16*)nullptr,
        (_Float16*)nullptr, (_Float16*)nullptr);
    gemm16m<<<448, 256, 0, stream>>>(
        xnH, xnL, peH, peL, w_tok, w_pos,
        KtfH, KtfL, KpfH, KpfL, QH, QL, posQH, posQL, Vf,
        1.0f / 32.0f, IS / 32.0f, 1.0f / 32.0f);
  }

  attn_mfma9<<<BB * NH * (SB / 128), 256, 0, stream>>>(
      KtfH, KtfL, KpfH, KpfL, QH, QL, posQH, posQL, Vf, bt, out);
}